// Round 11
// baseline (225.166 us; speedup 1.0000x reference)
//
#include <hip/hip_runtime.h>
#include <hip/hip_bf16.h>

constexpr int L = 8192;          // nodes
constexpr int H = 4;             // heads (both layers)

typedef __attribute__((ext_vector_type(8))) short bf16x8;
typedef __attribute__((ext_vector_type(8))) unsigned short u16x8;
typedef __attribute__((ext_vector_type(4))) float f32x4;

#if defined(__has_builtin)
#  if __has_builtin(__builtin_amdgcn_fdot2_f32_bf16)
#    define HAVE_DOT2 1
#  endif
#endif
#ifndef HAVE_DOT2
#  define HAVE_DOT2 0
#endif
#if HAVE_DOT2
typedef __attribute__((ext_vector_type(2))) __bf16 bfx2;
#endif

static __device__ __forceinline__ float lrelu(float e) {
  return e > 0.f ? e : 0.2f * e;
}
static __device__ __forceinline__ float b2f(unsigned short s) {
  return __uint_as_float(((unsigned)s) << 16);
}
static __device__ __forceinline__ unsigned short f2b(float f) {
  __hip_bfloat16 h = __float2bfloat16(f);
  return *reinterpret_cast<unsigned short*>(&h);
}

// per-edge channel-pair accumulate: hv[p] holds channels (2p,2p+1) as packed
// bf16; m.x = (alpha,0), m.y = (0,alpha) packed bf16 masks.
template<int PAIRS>
static __device__ __forceinline__ void edge_fma(const unsigned* hv, uint2 m, float* acc) {
#if HAVE_DOT2
#pragma unroll
  for (int p = 0; p < PAIRS; p++) {
    acc[2 * p]     = __builtin_amdgcn_fdot2_f32_bf16(
        __builtin_bit_cast(bfx2, hv[p]), __builtin_bit_cast(bfx2, m.x), acc[2 * p], false);
    acc[2 * p + 1] = __builtin_amdgcn_fdot2_f32_bf16(
        __builtin_bit_cast(bfx2, hv[p]), __builtin_bit_cast(bfx2, m.y), acc[2 * p + 1], false);
  }
#else
  float af = b2f((unsigned short)(m.x & 0xffffu));
#pragma unroll
  for (int p = 0; p < PAIRS; p++) {
    acc[2 * p]     = fmaf(af, b2f((unsigned short)(hv[p] & 0xffffu)), acc[2 * p]);
    acc[2 * p + 1] = fmaf(af, b2f((unsigned short)(hv[p] >> 16)), acc[2 * p + 1]);
  }
#endif
}

// ========== merged: LDS-tiled transposes (blocks 0..991) + elementwise tail ====
__global__ __launch_bounds__(256) void conv_combo(
    const float* __restrict__ seq, const float* __restrict__ W1,
    const float* __restrict__ W2, const float* __restrict__ Wg1,
    const float* __restrict__ Wg2, const float* __restrict__ fcW,
    const float* __restrict__ outW, const int* __restrict__ ei,
    const float* __restrict__ as1, const float* __restrict__ ad1,
    const float* __restrict__ as2, const float* __restrict__ ad2,
    int E, int Etot,
    __hip_bfloat16* __restrict__ xb, __hip_bfloat16* __restrict__ W1t,
    __hip_bfloat16* __restrict__ W2t, __hip_bfloat16* __restrict__ Wg1t,
    __hip_bfloat16* __restrict__ Wg2t, float* __restrict__ fcWt,
    float* __restrict__ outWt, float* __restrict__ wa2,
    int* __restrict__ deg, int* __restrict__ rank) {
  __shared__ float tile[32][33];
  if (blockIdx.x < 992) {
    int b = blockIdx.x;
    const float* src; void* dst; bool obf16; int K, N, Kout, kt, nt;
    if (b < 256)               { src = W2;  dst = W2t;  obf16 = true;  K = 1024; N = 256; Kout = 1024; nt = b & 7;  kt = b >> 3; }
    else if ((b -= 256) < 64)  { src = Wg1; dst = Wg1t; obf16 = true;  K = 256;  N = 256; Kout = 256;  nt = b & 7;  kt = b >> 3; }
    else if ((b -= 64) < 128)  { src = Wg2; dst = Wg2t; obf16 = true;  K = 256;  N = 512; Kout = 256;  nt = b & 15; kt = b >> 4; }
    else if ((b -= 128) < 256) { src = fcW; dst = fcWt; obf16 = false; K = 512;  N = 512; Kout = 512;  nt = b & 15; kt = b >> 4; }
    else if ((b -= 256) < 256) { src = outW;dst = outWt;obf16 = false; K = 512;  N = 489; Kout = 512;  nt = b & 15; kt = b >> 4; }
    else { b -= 256;             src = W1;  dst = W1t;  obf16 = true;  K = 26;   N = 1024;Kout = 32;   nt = b;      kt = 0; }
    int t = threadIdx.x;
    int lr = t >> 3, lc4 = (t & 7) * 4;
    int gk = kt * 32 + lr, gn = nt * 32 + lc4;
    float4 v = {0.f, 0.f, 0.f, 0.f};
    if (gk < K) {
      const float* p = &src[(size_t)gk * N + gn];
      v.x = (gn + 0 < N) ? p[0] : 0.f;
      v.y = (gn + 1 < N) ? p[1] : 0.f;
      v.z = (gn + 2 < N) ? p[2] : 0.f;
      v.w = (gn + 3 < N) ? p[3] : 0.f;
    }
    tile[lr][lc4 + 0] = v.x; tile[lr][lc4 + 1] = v.y;
    tile[lr][lc4 + 2] = v.z; tile[lr][lc4 + 3] = v.w;
    __syncthreads();
    int on = nt * 32 + lr, ok = kt * 32 + lc4;
    if (on >= N || ok >= Kout) return;
    float o0 = tile[lc4 + 0][lr], o1 = tile[lc4 + 1][lr];
    float o2 = tile[lc4 + 2][lr], o3 = tile[lc4 + 3][lr];
    if (obf16) {
      ushort4 u = {f2b(o0), f2b(o1), f2b(o2), f2b(o3)};
      *(ushort4*)&((__hip_bfloat16*)dst)[(size_t)on * Kout + ok] = u;
    } else {
      float4 u = {o0, o1, o2, o3};
      *(float4*)&((float*)dst)[(size_t)on * Kout + ok] = u;
    }
    return;
  }
  int i = (blockIdx.x - 992) * 256 + threadIdx.x;
  if (i < 262144) { int r = i >> 5, k = i & 31;
    xb[i] = __float2bfloat16(k < 26 ? seq[r * 26 + k] : 0.f); return; }
  i -= 262144;
  if (i < 2048) {  // Wg1t extension rows 256..263: wa1[k][o] in bf16
    int k = i >> 3, o = i & 7, h = o & 3;
    const float* av = (o < 4) ? as1 : ad1;
    float s = 0.f;
    for (int c = 0; c < 64; c++) s += Wg1[k * 256 + h * 64 + c] * av[h * 64 + c];
    Wg1t[(size_t)(256 + o) * 256 + k] = __float2bfloat16(s); return; }
  i -= 2048;
  if (i < 2048) {  // wa2 f32 (for gat1's fused a_sd2 epilogue)
    int k = i >> 3, o = i & 7, h = o & 3;
    const float* av = (o < 4) ? as2 : ad2;
    float s = 0.f;
    for (int c = 0; c < 128; c++) s += Wg2[k * 512 + h * 128 + c] * av[h * 128 + c];
    wa2[i] = s; return; }
  i -= 2048;
  if (i < 14336) {  // Wg1t zero rows 264..319
    ((__hip_bfloat16*)Wg1t)[(size_t)264 * 256 + i] = __float2bfloat16(0.f); return; }
  i -= 14336;
  if (i < Etot) {
    int dst = (i < E) ? ei[E + i] : (i - E);
    rank[i] = atomicAdd(&deg[dst], 1);
  }
}

// ============ bf16 MFMA GEMM: C = op(A[M,K] @ Bt[*,K]^T), 128x64 tile =========
template<int BK, bool RELU, bool ASD>
__global__ __launch_bounds__(256) void gemm_big(
    const __hip_bfloat16* __restrict__ A, const __hip_bfloat16* __restrict__ Bt,
    __hip_bfloat16* __restrict__ C, float* __restrict__ asd,
    int M, int N, int K) {
  __shared__ __align__(16) short As[128][BK + 8];
  __shared__ __align__(16) short Bs[64][BK + 8];
  int tid = threadIdx.x;
  int m0 = blockIdx.y * 128, n0 = blockIdx.x * 64;
  int w = tid >> 6, lane = tid & 63;
  int wm = (w >> 1) * 64, wn = (w & 1) * 32;
  f32x4 acc[4][2] = {};
  for (int k0 = 0; k0 < K; k0 += BK) {
    if constexpr (BK == 64) {
#pragma unroll
      for (int i = 0; i < 4; i++) {
        int ch = i * 256 + tid; int r = ch >> 3, kg = ch & 7;
        *(bf16x8*)&As[r][kg * 8] = *(const bf16x8*)&A[(size_t)(m0 + r) * K + k0 + kg * 8];
      }
#pragma unroll
      for (int i = 0; i < 2; i++) {
        int ch = i * 256 + tid; int r = ch >> 3, kg = ch & 7;
        *(bf16x8*)&Bs[r][kg * 8] = *(const bf16x8*)&Bt[(size_t)(n0 + r) * K + k0 + kg * 8];
      }
    } else {  // BK == 32
#pragma unroll
      for (int i = 0; i < 2; i++) {
        int ch = i * 256 + tid; int r = ch >> 2, kg = ch & 3;
        *(bf16x8*)&As[r][kg * 8] = *(const bf16x8*)&A[(size_t)(m0 + r) * K + k0 + kg * 8];
      }
      { int r = tid >> 2, kg = tid & 3;
        *(bf16x8*)&Bs[r][kg * 8] = *(const bf16x8*)&Bt[(size_t)(n0 + r) * K + k0 + kg * 8]; }
    }
    __syncthreads();
    int kk = (lane >> 4) * 8;
#pragma unroll
    for (int ks = 0; ks < BK / 32; ks++) {
      bf16x8 af[4], bfr[2];
#pragma unroll
      for (int m = 0; m < 4; m++)
        af[m] = *(const bf16x8*)&As[wm + m * 16 + (lane & 15)][ks * 32 + kk];
#pragma unroll
      for (int n = 0; n < 2; n++)
        bfr[n] = *(const bf16x8*)&Bs[wn + n * 16 + (lane & 15)][ks * 32 + kk];
#pragma unroll
      for (int m = 0; m < 4; m++)
#pragma unroll
        for (int n = 0; n < 2; n++)
          acc[m][n] = __builtin_amdgcn_mfma_f32_16x16x32_bf16(af[m], bfr[n], acc[m][n], 0, 0, 0);
    }
    __syncthreads();
  }
#pragma unroll
  for (int m = 0; m < 4; m++) {
#pragma unroll
    for (int n = 0; n < 2; n++) {
      int col = n0 + wn + n * 16 + (lane & 15);
#pragma unroll
      for (int j = 0; j < 4; j++) {
        int row = m0 + wm + m * 16 + (lane >> 4) * 4 + j;
        float v = acc[m][n][j];
        if (RELU) v = fmaxf(v, 0.f);
        if (!ASD) {
          C[(size_t)row * N + col] = __float2bfloat16(v);
        } else {
          if (col < N) C[(size_t)row * N + col] = __float2bfloat16(v);
          else if (col < N + 8) asd[(size_t)row * 8 + (col - N)] = v;
        }
      }
    }
  }
}

// ================= CSR build: shuffle-based scan (1 barrier) =================
__global__ __launch_bounds__(1024) void scan_deg(const int* __restrict__ deg,
                                                 int* __restrict__ row_start,
                                                 float* __restrict__ pooled) {
  __shared__ int wsum[16];
  int t = threadIdx.x;
  if (t < 512) pooled[t] = 0.f;
  int lane = t & 63, w = t >> 6;
  int local[8];
  int sum = 0;
#pragma unroll
  for (int j = 0; j < 8; j++) { local[j] = deg[t * 8 + j]; sum += local[j]; }
  int v = sum;
#pragma unroll
  for (int off = 1; off < 64; off <<= 1) {
    int u = __shfl_up(v, off);
    if (lane >= off) v += u;
  }
  if (lane == 63) wsum[w] = v;
  __syncthreads();
  int woff = 0;
  for (int i = 0; i < w; i++) woff += wsum[i];
  int base = woff + v - sum;   // exclusive prefix
#pragma unroll
  for (int j = 0; j < 8; j++) { row_start[t * 8 + j] = base; base += local[j]; }
  if (t == 1023) row_start[L] = base;
}

// atomic-free scatter using precomputed ranks
__global__ void scatter_edges(const int* __restrict__ ei, int E, int Etot,
                              const int* __restrict__ row_start,
                              const int* __restrict__ rank, int* __restrict__ csr_src) {
  int e = blockIdx.x * blockDim.x + threadIdx.x;
  if (e >= Etot) return;
  int srcv, dstv;
  if (e < E) { srcv = ei[e]; dstv = ei[E + e]; } else { srcv = dstv = e - E; }
  csr_src[row_start[dstv] + rank[e]] = srcv;
}

// ====== fused softmax+aggregate; edge-split x2 + double-buffered gather ========
// One node per 128-thread block; wave w handles half the node's edge range.
// acc = sum_j exp(e_j)*h[src_j] (unnormalized) + denom; waves combine partial
// sums via LDS + one barrier; divide at end. PHASES splits channels across
// blockIdx.y so the per-phase gathered table is <= 4MB (one XCD L2).
// Inner loop: ping-pong hvA/hvB batches so ~2*BATCH loads stay in flight.
// ASD2: layer-1 instance also emits a_sd2 = relu_out1 @ wa2.
template<int C, int PHASES, bool ASD2>
__global__ __launch_bounds__(128) void gat_fused(
    const __hip_bfloat16* __restrict__ hfeat, const float* __restrict__ a_sd,
    const int* __restrict__ row_start, const int* __restrict__ csr_src,
    const float* __restrict__ bias, __hip_bfloat16* __restrict__ out,
    const float* __restrict__ wa2, float* __restrict__ a_sd2) {
  constexpr int HC = 4 * C;
  constexpr int VEC = HC / PHASES / 64;   // 4 for both layers
  constexpr int PAIRS = VEC / 2;          // 2
  constexpr int BATCH = 8;                // per-buffer gathers (2 bufs in flight)
  int wid = threadIdx.x >> 6, lane = threadIdx.x & 63;
  int n = blockIdx.x;
  int c0 = blockIdx.y * 256 + lane * VEC;
  int hl = (c0 / C) & 3;
  int rs0 = row_start[n], re0 = row_start[n + 1];
  int degn = re0 - rs0;
  int halfd = (degn + 1) >> 1;
  int rs = rs0 + wid * halfd;
  int re = min(re0, rs + halfd);
  float4 ad4 = *(const float4*)&a_sd[(size_t)n * 8 + 4];

  __shared__ __align__(16) uint2 s_m[2][64][4];   // per-wave alpha masks (4KB)
  __shared__ float s_acc[64][VEC];                // wave-1 partial acc (1KB)
  __shared__ float s_dp[4];                       // wave-1 partial denominators
  float dp[4] = {0.f, 0.f, 0.f, 0.f};
  float acc[VEC] = {};
  const unsigned short* hbase = (const unsigned short*)hfeat;

  // prologue: chunk-0 csr + a_sd (this wave's range)
  int base = rs;
  int cnt = min(64, re - rs);
  int srcv = 0;
  float4 as4 = {0.f, 0.f, 0.f, 0.f};
  if (lane < cnt) {
    srcv = csr_src[rs + lane];
    as4 = *(const float4*)&a_sd[(size_t)srcv * 8];
  }

  while (base < re) {
    float w0 = 0.f, w1 = 0.f, w2 = 0.f, w3 = 0.f;
    if (lane < cnt) {
      w0 = __expf(lrelu(as4.x + ad4.x));
      w1 = __expf(lrelu(as4.y + ad4.y));
      w2 = __expf(lrelu(as4.z + ad4.z));
      w3 = __expf(lrelu(as4.w + ad4.w));
    }
    dp[0] += w0; dp[1] += w1; dp[2] += w2; dp[3] += w3;
    unsigned l0 = f2b(w0), l1 = f2b(w1), l2 = f2b(w2), l3 = f2b(w3);
    uint4 ma = {l0, l0 << 16, l1, l1 << 16};
    uint4 mb = {l2, l2 << 16, l3, l3 << 16};
    *(uint4*)&s_m[wid][lane][0] = ma;
    *(uint4*)&s_m[wid][lane][2] = mb;
    // within-wave LDS write->read ordering (waves touch disjoint s_m halves)
    asm volatile("s_waitcnt lgkmcnt(0)" ::: "memory");
    int cur_src = srcv;
    int cur_cnt = cnt;
    // prefetch next chunk's csr (independent coalesced load)
    int nbase = base + 64;
    bool have_next = nbase < re;
    cnt = min(64, re - nbase);
    srcv = 0;
    if (have_next && lane < cnt) srcv = csr_src[nbase + lane];
    float4 nas4 = {0.f, 0.f, 0.f, 0.f};

    unsigned hvA[BATCH][PAIRS], hvB[BATCH][PAIRS];
    auto issue = [&](unsigned (&hv)[BATCH][PAIRS], int jb) {
#pragma unroll
      for (int k = 0; k < BATCH; k++) {
        int sr = __builtin_amdgcn_readlane(cur_src, jb + k);
        *(uint2*)&hv[k][0] = *(const uint2*)&hbase[(size_t)sr * HC + c0];
      }
    };
    auto consume = [&](unsigned (&hv)[BATCH][PAIRS], int jb) {
#pragma unroll
      for (int k = 0; k < BATCH; k++) {
        uint2 m = s_m[wid][jb + k][hl];
        edge_fma<PAIRS>(hv[k], m, acc);
      }
    };

    int j = 0;
    if (j + BATCH <= cur_cnt) issue(hvA, j);
    if (have_next && lane < cnt)   // csr prefetch just issued; a_sd follows it
      nas4 = *(const float4*)&a_sd[(size_t)srcv * 8];
    for (; j + 2 * BATCH <= cur_cnt; j += 2 * BATCH) {
      issue(hvB, j + BATCH);
      consume(hvA, j);
      if (j + 3 * BATCH <= cur_cnt) issue(hvA, j + 2 * BATCH);
      consume(hvB, j + BATCH);
    }
    if (j + BATCH <= cur_cnt) { consume(hvA, j); j += BATCH; }
    for (; j < cur_cnt; j++) {
      int sr = __builtin_amdgcn_readlane(cur_src, j);
      unsigned hv[PAIRS];
      *(uint2*)&hv[0] = *(const uint2*)&hbase[(size_t)sr * HC + c0];
      uint2 m = s_m[wid][j][hl];
      edge_fma<PAIRS>(hv, m, acc);
    }
    as4 = nas4;
    base = nbase;
  }

  // ---- per-wave denominator butterfly ----
#pragma unroll
  for (int off = 32; off > 0; off >>= 1) {
#pragma unroll
    for (int h = 0; h < 4; h++) dp[h] += __shfl_xor(dp[h], off);
  }

  // ---- cross-wave combine: wave 1 deposits partials, wave 0 reduces ----
  if (wid == 1) {
#pragma unroll
    for (int k = 0; k < VEC; k++) s_acc[lane][k] = acc[k];
    if (lane == 0) { s_dp[0] = dp[0]; s_dp[1] = dp[1]; s_dp[2] = dp[2]; s_dp[3] = dp[3]; }
  }
  __syncthreads();
  if (wid == 1) return;
#pragma unroll
  for (int k = 0; k < VEC; k++) acc[k] += s_acc[lane][k];
  float dsel = (hl == 0 ? dp[0] : hl == 1 ? dp[1] : hl == 2 ? dp[2] : dp[3]) + s_dp[hl];
  float inv = 1.f / (dsel + 1e-16f);

  // ---- epilogue ----
#pragma unroll
  for (int k = 0; k < VEC; k++)
    acc[k] = fmaxf(fmaf(acc[k], inv, bias[c0 + k]), 0.f);
  unsigned short* op = (unsigned short*)out + (size_t)n * HC + c0;
  ushort4 ov = {f2b(acc[0]), f2b(acc[1]), f2b(acc[2]), f2b(acc[3])};
  *(ushort4*)op = ov;

  // ---- fused a_sd2 = relu_out1[n] @ wa2 (layer-1 instance only) ----
  if constexpr (ASD2) {
    float p[8] = {};
#pragma unroll
    for (int q = 0; q < VEC; q++) {
      const float* wr = &wa2[(size_t)(c0 + q) * 8];
#pragma unroll
      for (int o = 0; o < 8; o++) p[o] = fmaf(acc[q], wr[o], p[o]);
    }
#pragma unroll
    for (int off = 32; off > 0; off >>= 1) {
#pragma unroll
      for (int o = 0; o < 8; o++) p[o] += __shfl_xor(p[o], off);
    }
    if (lane == 0) {
      float4 p0 = {p[0], p[1], p[2], p[3]};
      float4 p1 = {p[4], p[5], p[6], p[7]};
      *(float4*)&a_sd2[(size_t)n * 8 + 0] = p0;
      *(float4*)&a_sd2[(size_t)n * 8 + 4] = p1;
    }
  }
}

// ================= pooled column sum (bf16 in, f32 atomic out) =================
__global__ __launch_bounds__(512) void col_sum_bf16(const __hip_bfloat16* __restrict__ x,
                                                    float* __restrict__ pooled) {
  int t = threadIdx.x;
  float acc = 0.f;
  for (int r = blockIdx.x; r < L; r += 64)
    acc += b2f(*(const unsigned short*)&x[(size_t)r * 512 + t]);
  atomicAdd(&pooled[t], acc);
}

// ================= FC head (pre-transposed f32 weights) =================
__global__ __launch_bounds__(256) void fc1(const float* __restrict__ pooled,
                                           const float* __restrict__ Wt,
                                           const float* __restrict__ b,
                                           float* __restrict__ out) {
  __shared__ float pv[512];
  __shared__ float red[256];
  int t = threadIdx.x;
  pv[t] = pooled[t]; pv[t + 256] = pooled[t + 256];
  __syncthreads();
  int ol = t >> 4;
  int o = blockIdx.x * 16 + ol;
  int ks = (t & 15) * 32;
  float p = 0.f;
  const float* wr = &Wt[(size_t)o * 512 + ks];
#pragma unroll
  for (int kk = 0; kk < 32; kk++) p = fmaf(pv[ks + kk], wr[kk], p);
  red[t] = p;
  __syncthreads();
  if ((t & 15) == 0) {
    float s2 = 0.f;
#pragma unroll
    for (int i = 0; i < 16; i++) s2 += red[ol * 16 + i];
    out[o] = fmaxf(s2 + b[o], 0.f);
  }
}

__global__ __launch_bounds__(256) void fc2(const float* __restrict__ h,
                                           const float* __restrict__ Wt,
                                           const float* __restrict__ outb,
                                           float* __restrict__ out) {
  __shared__ float pv[512];
  __shared__ float red[256];
  int t = threadIdx.x;
  pv[t] = h[t]; pv[t + 256] = h[t + 256];
  __syncthreads();
  int ol = t >> 4;
  int o = blockIdx.x * 16 + ol;
  int ks = (t & 15) * 32;
  float p = 0.f;
  const float* wr = &Wt[(size_t)o * 512 + ks];
#pragma unroll
  for (int kk = 0; kk < 32; kk++) p = fmaf(pv[ks + kk], wr[kk], p);
  red[t] = p;
  __syncthreads();
  if ((t & 15) == 0 && o < 489) {
    float s2 = 0.f;
#pragma unroll
    for (int i = 0; i < 16; i++) s2 += red[ol * 16 + i];
    out[o] = s2 + outb[o];
  }
}

extern "C" void kernel_launch(void* const* d_in, const int* in_sizes, int n_in,
                              void* d_out, int out_size, void* d_ws, size_t ws_size,
                              hipStream_t stream) {
  const float* seq   = (const float*)d_in[0];
  const int*   ei    = (const int*)d_in[1];
  const float* W1    = (const float*)d_in[2];
  const float* W2    = (const float*)d_in[3];
  const float* Wg1   = (const float*)d_in[4];
  const float* asrc1 = (const float*)d_in[5];
  const float* adst1 = (const float*)d_in[6];
  const float* b1    = (const float*)d_in[7];
  const float* Wg2   = (const float*)d_in[8];
  const float* asrc2 = (const float*)d_in[9];
  const float* adst2 = (const float*)d_in[10];
  const float* b2    = (const float*)d_in[11];
  const float* fcW   = (const float*)d_in[12];
  const float* fcb   = (const float*)d_in[13];
  const float* outW  = (const float*)d_in[14];
  const float* outb  = (const float*)d_in[15];
  float* outp = (float*)d_out;

  const int E = in_sizes[1] / 2;      // 524288
  const int Etot = E + L;             // + self loops

  // ---- workspace layout ----
  char* ws = (char*)d_ws;
  __hip_bfloat16* mlp1 = (__hip_bfloat16*)(ws + 0);           // [L,1024] 16MB (dead after gemm2)
  __hip_bfloat16* out2 = (__hip_bfloat16*)(ws + 0);           // [L,512] 8MB
  __hip_bfloat16* h2   = (__hip_bfloat16*)(ws + (16u << 20)); // [L,512] 8MB
  __hip_bfloat16* x0   = (__hip_bfloat16*)(ws + (24u << 20)); // [L,256] 4MB
  __hip_bfloat16* h1   = (__hip_bfloat16*)(ws + (28u << 20)); // [L,256] 4MB
  __hip_bfloat16* out1 = (__hip_bfloat16*)(ws + (32u << 20)); // [L,256] 4MB
  size_t off = (36u << 20);
  __hip_bfloat16* xb   = (__hip_bfloat16*)(ws + off); off += (size_t)L * 32 * 2;
  __hip_bfloat16* W1t  = (__hip_bfloat16*)(ws + off); off += (size_t)1024 * 32 * 2;
  __hip_bfloat16* W2t  = (__hip_bfloat16*)(ws + off); off += (size_t)256 * 1024 * 2;
  __hip_bfloat16* Wg1t = (__hip_bfloat16*)(ws + off); off += (size_t)320 * 256 * 2;  // extended
  __hip_bfloat16* Wg2t = (__hip_bfloat16*)(ws + off); off += (size_t)512 * 256 * 2;
  float* fcWt  = (float*)(ws + off); off += (size_t)512 * 512 * 4;
  float* outWt = (float*)(ws + off); off += (size_t)512 * 512 * 4;
  int* csr_src = (int*)(ws + off); off += (size_t)Etot * 4;
  int* rank    = (int*)(ws + off); off += (size_t)Etot * 4;
  off = (off + 255) & ~(size_t)255;
  int* row_start = (int*)(ws + off); off += (size_t)(L + 1) * 4;
  off = (off + 255) & ~(size_t)255;
  int* deg    = (int*)(ws + off); off += (size_t)L * 4;
  float* a_sd1 = (float*)(ws + off); off += (size_t)L * 8 * 4;
  float* a_sd2 = (float*)(ws + off); off += (size_t)L * 8 * 4;
  float* wa2 = (float*)(ws + off); off += 2048 * 4;
  float* pooled = (float*)(ws + off); off += 512 * 4;
  float* hbuf   = (float*)(ws + off); off += 512 * 4;

  // ---- zero deg ----
  hipMemsetAsync(deg, 0, (size_t)L * 4, stream);

  // ---- merged transposes + conversions + wa + degree/rank ----
  int convN = 262144 + 2048 + 2048 + 14336 + Etot;
  int convB = (convN + 255) / 256;
  conv_combo<<<992 + convB, 256, 0, stream>>>(
      seq, W1, W2, Wg1, Wg2, fcW, outW, ei, asrc1, adst1, asrc2, adst2, E, Etot,
      xb, W1t, W2t, Wg1t, Wg2t, fcWt, outWt, wa2, deg, rank);

  // ---- CSR ----
  scan_deg<<<1, 1024, 0, stream>>>(deg, row_start, pooled);
  scatter_edges<<<(Etot + 255) / 256, 256, 0, stream>>>(ei, E, Etot, row_start, rank, csr_src);

  // ---- input MLP ----
  gemm_big<32, true, false><<<dim3(16, 64), 256, 0, stream>>>(xb, W1t, mlp1, nullptr, L, 1024, 32);
  gemm_big<64, false, false><<<dim3(4, 64), 256, 0, stream>>>(mlp1, W2t, x0, nullptr, L, 256, 1024);

  // ---- GAT layer 1 (C=64): h1 GEMM also emits a_sd1 via extended Wg1t ----
  gemm_big<64, false, true><<<dim3(5, 64), 256, 0, stream>>>(x0, Wg1t, h1, a_sd1, L, 256, 256);
  gat_fused<64, 1, true><<<dim3(L, 1), 128, 0, stream>>>(h1, a_sd1, row_start, csr_src, b1, out1, wa2, a_sd2);

  // ---- GAT layer 2 (C=128): 2-phase L2-resident gather, edge-split x2 ----
  gemm_big<64, false, false><<<dim3(8, 64), 256, 0, stream>>>(out1, Wg2t, h2, nullptr, L, 512, 256);
  gat_fused<128, 2, false><<<dim3(L, 2), 128, 0, stream>>>(h2, a_sd2, row_start, csr_src, b2, out2, nullptr, nullptr);

  // ---- pool + FC head ----
  col_sum_bf16<<<64, 512, 0, stream>>>(out2, pooled);
  fc1<<<32, 256, 0, stream>>>(pooled, fcWt, fcb, hbuf);
  fc2<<<31, 256, 0, stream>>>(hbuf, outWt, outb, outp);
}

// Round 12
// 184.214 us; speedup vs baseline: 1.2223x; 1.2223x over previous
//
#include <hip/hip_runtime.h>
#include <hip/hip_bf16.h>

constexpr int L = 8192;          // nodes
constexpr int H = 4;             // heads (both layers)

typedef __attribute__((ext_vector_type(8))) short bf16x8;
typedef __attribute__((ext_vector_type(8))) unsigned short u16x8;
typedef __attribute__((ext_vector_type(4))) float f32x4;

#if defined(__has_builtin)
#  if __has_builtin(__builtin_amdgcn_fdot2_f32_bf16)
#    define HAVE_DOT2 1
#  endif
#endif
#ifndef HAVE_DOT2
#  define HAVE_DOT2 0
#endif
#if HAVE_DOT2
typedef __attribute__((ext_vector_type(2))) __bf16 bfx2;
#endif

static __device__ __forceinline__ float lrelu(float e) {
  return e > 0.f ? e : 0.2f * e;
}
static __device__ __forceinline__ float b2f(unsigned short s) {
  return __uint_as_float(((unsigned)s) << 16);
}
static __device__ __forceinline__ unsigned short f2b(float f) {
  __hip_bfloat16 h = __float2bfloat16(f);
  return *reinterpret_cast<unsigned short*>(&h);
}

// per-edge channel-pair accumulate: hv[p] holds channels (2p,2p+1) as packed
// bf16; m.x = (alpha,0), m.y = (0,alpha) packed bf16 masks.
template<int PAIRS>
static __device__ __forceinline__ void edge_fma(const unsigned* hv, uint2 m, float* acc) {
#if HAVE_DOT2
#pragma unroll
  for (int p = 0; p < PAIRS; p++) {
    acc[2 * p]     = __builtin_amdgcn_fdot2_f32_bf16(
        __builtin_bit_cast(bfx2, hv[p]), __builtin_bit_cast(bfx2, m.x), acc[2 * p], false);
    acc[2 * p + 1] = __builtin_amdgcn_fdot2_f32_bf16(
        __builtin_bit_cast(bfx2, hv[p]), __builtin_bit_cast(bfx2, m.y), acc[2 * p + 1], false);
  }
#else
  float af = b2f((unsigned short)(m.x & 0xffffu));
#pragma unroll
  for (int p = 0; p < PAIRS; p++) {
    acc[2 * p]     = fmaf(af, b2f((unsigned short)(hv[p] & 0xffffu)), acc[2 * p]);
    acc[2 * p + 1] = fmaf(af, b2f((unsigned short)(hv[p] >> 16)), acc[2 * p + 1]);
  }
#endif
}

// ========== merged: LDS-tiled transposes (blocks 0..991) + elementwise tail ====
__global__ __launch_bounds__(256) void conv_combo(
    const float* __restrict__ seq, const float* __restrict__ W1,
    const float* __restrict__ W2, const float* __restrict__ Wg1,
    const float* __restrict__ Wg2, const float* __restrict__ fcW,
    const float* __restrict__ outW, const int* __restrict__ ei,
    const float* __restrict__ as1, const float* __restrict__ ad1,
    const float* __restrict__ as2, const float* __restrict__ ad2,
    int E, int Etot,
    __hip_bfloat16* __restrict__ xb, __hip_bfloat16* __restrict__ W1t,
    __hip_bfloat16* __restrict__ W2t, __hip_bfloat16* __restrict__ Wg1t,
    __hip_bfloat16* __restrict__ Wg2t, float* __restrict__ fcWt,
    float* __restrict__ outWt, float* __restrict__ wa2,
    int* __restrict__ deg, int* __restrict__ rank) {
  __shared__ float tile[32][33];
  if (blockIdx.x < 992) {
    int b = blockIdx.x;
    const float* src; void* dst; bool obf16; int K, N, Kout, kt, nt;
    if (b < 256)               { src = W2;  dst = W2t;  obf16 = true;  K = 1024; N = 256; Kout = 1024; nt = b & 7;  kt = b >> 3; }
    else if ((b -= 256) < 64)  { src = Wg1; dst = Wg1t; obf16 = true;  K = 256;  N = 256; Kout = 256;  nt = b & 7;  kt = b >> 3; }
    else if ((b -= 64) < 128)  { src = Wg2; dst = Wg2t; obf16 = true;  K = 256;  N = 512; Kout = 256;  nt = b & 15; kt = b >> 4; }
    else if ((b -= 128) < 256) { src = fcW; dst = fcWt; obf16 = false; K = 512;  N = 512; Kout = 512;  nt = b & 15; kt = b >> 4; }
    else if ((b -= 256) < 256) { src = outW;dst = outWt;obf16 = false; K = 512;  N = 489; Kout = 512;  nt = b & 15; kt = b >> 4; }
    else { b -= 256;             src = W1;  dst = W1t;  obf16 = true;  K = 26;   N = 1024;Kout = 32;   nt = b;      kt = 0; }
    int t = threadIdx.x;
    int lr = t >> 3, lc4 = (t & 7) * 4;
    int gk = kt * 32 + lr, gn = nt * 32 + lc4;
    float4 v = {0.f, 0.f, 0.f, 0.f};
    if (gk < K) {
      const float* p = &src[(size_t)gk * N + gn];
      v.x = (gn + 0 < N) ? p[0] : 0.f;
      v.y = (gn + 1 < N) ? p[1] : 0.f;
      v.z = (gn + 2 < N) ? p[2] : 0.f;
      v.w = (gn + 3 < N) ? p[3] : 0.f;
    }
    tile[lr][lc4 + 0] = v.x; tile[lr][lc4 + 1] = v.y;
    tile[lr][lc4 + 2] = v.z; tile[lr][lc4 + 3] = v.w;
    __syncthreads();
    int on = nt * 32 + lr, ok = kt * 32 + lc4;
    if (on >= N || ok >= Kout) return;
    float o0 = tile[lc4 + 0][lr], o1 = tile[lc4 + 1][lr];
    float o2 = tile[lc4 + 2][lr], o3 = tile[lc4 + 3][lr];
    if (obf16) {
      ushort4 u = {f2b(o0), f2b(o1), f2b(o2), f2b(o3)};
      *(ushort4*)&((__hip_bfloat16*)dst)[(size_t)on * Kout + ok] = u;
    } else {
      float4 u = {o0, o1, o2, o3};
      *(float4*)&((float*)dst)[(size_t)on * Kout + ok] = u;
    }
    return;
  }
  int i = (blockIdx.x - 992) * 256 + threadIdx.x;
  if (i < 262144) { int r = i >> 5, k = i & 31;
    xb[i] = __float2bfloat16(k < 26 ? seq[r * 26 + k] : 0.f); return; }
  i -= 262144;
  if (i < 2048) {  // Wg1t extension rows 256..263: wa1[k][o] in bf16
    int k = i >> 3, o = i & 7, h = o & 3;
    const float* av = (o < 4) ? as1 : ad1;
    float s = 0.f;
    for (int c = 0; c < 64; c++) s += Wg1[k * 256 + h * 64 + c] * av[h * 64 + c];
    Wg1t[(size_t)(256 + o) * 256 + k] = __float2bfloat16(s); return; }
  i -= 2048;
  if (i < 2048) {  // wa2 f32 (for gat1's fused a_sd2 epilogue)
    int k = i >> 3, o = i & 7, h = o & 3;
    const float* av = (o < 4) ? as2 : ad2;
    float s = 0.f;
    for (int c = 0; c < 128; c++) s += Wg2[k * 512 + h * 128 + c] * av[h * 128 + c];
    wa2[i] = s; return; }
  i -= 2048;
  if (i < 14336) {  // Wg1t zero rows 264..319
    ((__hip_bfloat16*)Wg1t)[(size_t)264 * 256 + i] = __float2bfloat16(0.f); return; }
  i -= 14336;
  if (i < Etot) {
    int dst = (i < E) ? ei[E + i] : (i - E);
    rank[i] = atomicAdd(&deg[dst], 1);
  }
}

// ============ bf16 MFMA GEMM: C = op(A[M,K] @ Bt[*,K]^T), 128x64 tile =========
template<int BK, bool RELU, bool ASD>
__global__ __launch_bounds__(256) void gemm_big(
    const __hip_bfloat16* __restrict__ A, const __hip_bfloat16* __restrict__ Bt,
    __hip_bfloat16* __restrict__ C, float* __restrict__ asd,
    int M, int N, int K) {
  __shared__ __align__(16) short As[128][BK + 8];
  __shared__ __align__(16) short Bs[64][BK + 8];
  int tid = threadIdx.x;
  int m0 = blockIdx.y * 128, n0 = blockIdx.x * 64;
  int w = tid >> 6, lane = tid & 63;
  int wm = (w >> 1) * 64, wn = (w & 1) * 32;
  f32x4 acc[4][2] = {};
  for (int k0 = 0; k0 < K; k0 += BK) {
    if constexpr (BK == 64) {
#pragma unroll
      for (int i = 0; i < 4; i++) {
        int ch = i * 256 + tid; int r = ch >> 3, kg = ch & 7;
        *(bf16x8*)&As[r][kg * 8] = *(const bf16x8*)&A[(size_t)(m0 + r) * K + k0 + kg * 8];
      }
#pragma unroll
      for (int i = 0; i < 2; i++) {
        int ch = i * 256 + tid; int r = ch >> 3, kg = ch & 7;
        *(bf16x8*)&Bs[r][kg * 8] = *(const bf16x8*)&Bt[(size_t)(n0 + r) * K + k0 + kg * 8];
      }
    } else {  // BK == 32
#pragma unroll
      for (int i = 0; i < 2; i++) {
        int ch = i * 256 + tid; int r = ch >> 2, kg = ch & 3;
        *(bf16x8*)&As[r][kg * 8] = *(const bf16x8*)&A[(size_t)(m0 + r) * K + k0 + kg * 8];
      }
      { int r = tid >> 2, kg = tid & 3;
        *(bf16x8*)&Bs[r][kg * 8] = *(const bf16x8*)&Bt[(size_t)(n0 + r) * K + k0 + kg * 8]; }
    }
    __syncthreads();
    int kk = (lane >> 4) * 8;
#pragma unroll
    for (int ks = 0; ks < BK / 32; ks++) {
      bf16x8 af[4], bfr[2];
#pragma unroll
      for (int m = 0; m < 4; m++)
        af[m] = *(const bf16x8*)&As[wm + m * 16 + (lane & 15)][ks * 32 + kk];
#pragma unroll
      for (int n = 0; n < 2; n++)
        bfr[n] = *(const bf16x8*)&Bs[wn + n * 16 + (lane & 15)][ks * 32 + kk];
#pragma unroll
      for (int m = 0; m < 4; m++)
#pragma unroll
        for (int n = 0; n < 2; n++)
          acc[m][n] = __builtin_amdgcn_mfma_f32_16x16x32_bf16(af[m], bfr[n], acc[m][n], 0, 0, 0);
    }
    __syncthreads();
  }
#pragma unroll
  for (int m = 0; m < 4; m++) {
#pragma unroll
    for (int n = 0; n < 2; n++) {
      int col = n0 + wn + n * 16 + (lane & 15);
#pragma unroll
      for (int j = 0; j < 4; j++) {
        int row = m0 + wm + m * 16 + (lane >> 4) * 4 + j;
        float v = acc[m][n][j];
        if (RELU) v = fmaxf(v, 0.f);
        if (!ASD) {
          C[(size_t)row * N + col] = __float2bfloat16(v);
        } else {
          if (col < N) C[(size_t)row * N + col] = __float2bfloat16(v);
          else if (col < N + 8) asd[(size_t)row * 8 + (col - N)] = v;
        }
      }
    }
  }
}

// ====== per-head batched GEMM over agg2, fused bias+ReLU+column-sum ============
// out2 is never materialized: C-tile values are reduced per column and
// atomically added into pooled[512]. grid = (2, 64, 4heads).
__global__ __launch_bounds__(256) void gemm_head(
    const __hip_bfloat16* __restrict__ agg,   // [L, 4*256], head z at col z*256
    const __hip_bfloat16* __restrict__ Wg2t,  // [512, 256]; head z rows z*128..
    const float* __restrict__ b2,             // [512]
    float* __restrict__ pooled) {             // [512]
  constexpr int BK = 64;
  __shared__ __align__(16) short As[128][BK + 8];
  __shared__ __align__(16) short Bs[64][BK + 8];
  __shared__ float s_cs[4][32];
  int tid = threadIdx.x;
  int z = blockIdx.z;
  int m0 = blockIdx.y * 128, n0 = blockIdx.x * 64;   // n0 within head's 128
  const __hip_bfloat16* A = agg + (size_t)z * 256;
  const __hip_bfloat16* Bt = Wg2t + (size_t)z * 128 * 256;
  int w = tid >> 6, lane = tid & 63;
  int wm = (w >> 1) * 64, wn = (w & 1) * 32;
  f32x4 acc[4][2] = {};
  for (int k0 = 0; k0 < 256; k0 += BK) {
#pragma unroll
    for (int i = 0; i < 4; i++) {
      int ch = i * 256 + tid; int r = ch >> 3, kg = ch & 7;
      *(bf16x8*)&As[r][kg * 8] = *(const bf16x8*)&A[(size_t)(m0 + r) * 1024 + k0 + kg * 8];
    }
#pragma unroll
    for (int i = 0; i < 2; i++) {
      int ch = i * 256 + tid; int r = ch >> 3, kg = ch & 7;
      *(bf16x8*)&Bs[r][kg * 8] = *(const bf16x8*)&Bt[(size_t)(n0 + r) * 256 + k0 + kg * 8];
    }
    __syncthreads();
    int kk = (lane >> 4) * 8;
#pragma unroll
    for (int ks = 0; ks < BK / 32; ks++) {
      bf16x8 af[4], bfr[2];
#pragma unroll
      for (int m = 0; m < 4; m++)
        af[m] = *(const bf16x8*)&As[wm + m * 16 + (lane & 15)][ks * 32 + kk];
#pragma unroll
      for (int n = 0; n < 2; n++)
        bfr[n] = *(const bf16x8*)&Bs[wn + n * 16 + (lane & 15)][ks * 32 + kk];
#pragma unroll
      for (int m = 0; m < 4; m++)
#pragma unroll
        for (int n = 0; n < 2; n++)
          acc[m][n] = __builtin_amdgcn_mfma_f32_16x16x32_bf16(af[m], bfr[n], acc[m][n], 0, 0, 0);
    }
    __syncthreads();
  }
  // bias + relu + per-column partial sums over this block's 128 rows
  float cs[2] = {0.f, 0.f};
#pragma unroll
  for (int n = 0; n < 2; n++) {
    float bv = b2[z * 128 + n0 + wn + n * 16 + (lane & 15)];
#pragma unroll
    for (int m = 0; m < 4; m++)
#pragma unroll
      for (int j = 0; j < 4; j++)
        cs[n] += fmaxf(acc[m][n][j] + bv, 0.f);
  }
#pragma unroll
  for (int n = 0; n < 2; n++) {
    cs[n] += __shfl_xor(cs[n], 16);
    cs[n] += __shfl_xor(cs[n], 32);
  }
  if (lane < 16) { s_cs[w][lane] = cs[0]; s_cs[w][16 + lane] = cs[1]; }
  __syncthreads();
  if (tid < 64) {
    int c = tid;
    int bsel = c >> 5;   // cols 0-31: waves 0,2 ; cols 32-63: waves 1,3
    float s = s_cs[bsel][c & 31] + s_cs[bsel + 2][c & 31];
    atomicAdd(&pooled[z * 128 + n0 + c], s);
  }
}

// ================= CSR build: shuffle-based scan (1 barrier) =================
__global__ __launch_bounds__(1024) void scan_deg(const int* __restrict__ deg,
                                                 int* __restrict__ row_start,
                                                 float* __restrict__ pooled) {
  __shared__ int wsum[16];
  int t = threadIdx.x;
  if (t < 512) pooled[t] = 0.f;
  int lane = t & 63, w = t >> 6;
  int local[8];
  int sum = 0;
#pragma unroll
  for (int j = 0; j < 8; j++) { local[j] = deg[t * 8 + j]; sum += local[j]; }
  int v = sum;
#pragma unroll
  for (int off = 1; off < 64; off <<= 1) {
    int u = __shfl_up(v, off);
    if (lane >= off) v += u;
  }
  if (lane == 63) wsum[w] = v;
  __syncthreads();
  int woff = 0;
  for (int i = 0; i < w; i++) woff += wsum[i];
  int base = woff + v - sum;   // exclusive prefix
#pragma unroll
  for (int j = 0; j < 8; j++) { row_start[t * 8 + j] = base; base += local[j]; }
  if (t == 1023) row_start[L] = base;
}

// atomic-free scatter using precomputed ranks
__global__ void scatter_edges(const int* __restrict__ ei, int E, int Etot,
                              const int* __restrict__ row_start,
                              const int* __restrict__ rank, int* __restrict__ csr_src) {
  int e = blockIdx.x * blockDim.x + threadIdx.x;
  if (e >= Etot) return;
  int srcv, dstv;
  if (e < E) { srcv = ei[e]; dstv = ei[E + e]; } else { srcv = dstv = e - E; }
  csr_src[row_start[dstv] + rank[e]] = srcv;
}

// ====== layer-1 fused softmax+aggregate (round-10 structure, 2 nodes/block) ====
// acc = sum_j exp(e_j)*h[src_j] (unnormalized) + denom; divide at end.
// ASD2: also emits a_sd2 = relu_out1 @ wa2.
template<int C, bool ASD2>
__global__ __launch_bounds__(128) void gat_fused(
    const __hip_bfloat16* __restrict__ hfeat, const float* __restrict__ a_sd,
    const int* __restrict__ row_start, const int* __restrict__ csr_src,
    const float* __restrict__ bias, __hip_bfloat16* __restrict__ out,
    const float* __restrict__ wa2, float* __restrict__ a_sd2) {
  constexpr int HC = 4 * C;
  constexpr int VEC = HC / 64;            // 4
  constexpr int PAIRS = VEC / 2;          // 2
  constexpr int BATCH = 12;               // in-flight 8B row gathers
  int wid = threadIdx.x >> 6, lane = threadIdx.x & 63;
  int n = blockIdx.x * 2 + wid;
  int c0 = lane * VEC;
  int hl = (c0 / C) & 3;
  int rs = row_start[n], re = row_start[n + 1];
  float4 ad4 = *(const float4*)&a_sd[(size_t)n * 8 + 4];

  __shared__ __align__(16) uint2 s_m[2][64][4];   // expanded alpha masks (4KB)
  float dp[4] = {0.f, 0.f, 0.f, 0.f};
  float acc[VEC] = {};
  const unsigned short* hbase = (const unsigned short*)hfeat;

  int base = rs;
  int cnt = min(64, re - rs);
  int srcv = 0;
  float4 as4 = {0.f, 0.f, 0.f, 0.f};
  if (lane < cnt) {
    srcv = csr_src[rs + lane];
    as4 = *(const float4*)&a_sd[(size_t)srcv * 8];
  }

  while (base < re) {
    float w0 = 0.f, w1 = 0.f, w2 = 0.f, w3 = 0.f;
    if (lane < cnt) {
      w0 = __expf(lrelu(as4.x + ad4.x));
      w1 = __expf(lrelu(as4.y + ad4.y));
      w2 = __expf(lrelu(as4.z + ad4.z));
      w3 = __expf(lrelu(as4.w + ad4.w));
    }
    dp[0] += w0; dp[1] += w1; dp[2] += w2; dp[3] += w3;
    unsigned l0 = f2b(w0), l1 = f2b(w1), l2 = f2b(w2), l3 = f2b(w3);
    uint4 ma = {l0, l0 << 16, l1, l1 << 16};
    uint4 mb = {l2, l2 << 16, l3, l3 << 16};
    *(uint4*)&s_m[wid][lane][0] = ma;
    *(uint4*)&s_m[wid][lane][2] = mb;
    asm volatile("s_waitcnt lgkmcnt(0)" ::: "memory");
    int cur_src = srcv;
    int cur_cnt = cnt;
    int nbase = base + 64;
    bool have_next = nbase < re;
    cnt = min(64, re - nbase);
    srcv = 0;
    if (have_next && lane < cnt) srcv = csr_src[nbase + lane];
    float4 nas4 = {0.f, 0.f, 0.f, 0.f};
    bool did_asd = false;

    int j = 0;
    for (; j + BATCH <= cur_cnt; j += BATCH) {
      int srs[BATCH];
#pragma unroll
      for (int k = 0; k < BATCH; k++) srs[k] = __builtin_amdgcn_readlane(cur_src, j + k);
      unsigned hv[BATCH][PAIRS];
#pragma unroll
      for (int k = 0; k < BATCH; k++) {
        const unsigned short* hp = &hbase[(size_t)srs[k] * HC + c0];
        *(uint2*)&hv[k][0] = *(const uint2*)hp;
      }
      if (j == 0 && have_next) {
        if (lane < cnt) nas4 = *(const float4*)&a_sd[(size_t)srcv * 8];
        did_asd = true;
      }
#pragma unroll
      for (int k = 0; k < BATCH; k++) {
        uint2 m = s_m[wid][j + k][hl];
        edge_fma<PAIRS>(hv[k], m, acc);
      }
    }
    if (have_next && !did_asd && lane < cnt)
      nas4 = *(const float4*)&a_sd[(size_t)srcv * 8];
    for (; j < cur_cnt; j++) {
      int sr = __builtin_amdgcn_readlane(cur_src, j);
      unsigned hv[PAIRS];
      const unsigned short* hp = &hbase[(size_t)sr * HC + c0];
      *(uint2*)&hv[0] = *(const uint2*)hp;
      uint2 m = s_m[wid][j][hl];
      edge_fma<PAIRS>(hv, m, acc);
    }
    as4 = nas4;
    base = nbase;
  }

#pragma unroll
  for (int off = 32; off > 0; off >>= 1) {
#pragma unroll
    for (int h = 0; h < 4; h++) dp[h] += __shfl_xor(dp[h], off);
  }
  float dsel = hl == 0 ? dp[0] : hl == 1 ? dp[1] : hl == 2 ? dp[2] : dp[3];
  float inv = 1.f / (dsel + 1e-16f);

#pragma unroll
  for (int k = 0; k < VEC; k++)
    acc[k] = fmaxf(fmaf(acc[k], inv, bias[c0 + k]), 0.f);
  unsigned short* op = (unsigned short*)out + (size_t)n * HC + c0;
  ushort4 ov = {f2b(acc[0]), f2b(acc[1]), f2b(acc[2]), f2b(acc[3])};
  *(ushort4*)op = ov;

  if constexpr (ASD2) {
    float p[8] = {};
#pragma unroll
    for (int q = 0; q < VEC; q++) {
      const float* wr = &wa2[(size_t)(c0 + q) * 8];
#pragma unroll
      for (int o = 0; o < 8; o++) p[o] = fmaf(acc[q], wr[o], p[o]);
    }
#pragma unroll
    for (int off = 32; off > 0; off >>= 1) {
#pragma unroll
      for (int o = 0; o < 8; o++) p[o] += __shfl_xor(p[o], off);
    }
    if (lane == 0) {
      float4 p0 = {p[0], p[1], p[2], p[3]};
      float4 p1 = {p[4], p[5], p[6], p[7]};
      *(float4*)&a_sd2[(size_t)n * 8 + 0] = p0;
      *(float4*)&a_sd2[(size_t)n * 8 + 4] = p1;
    }
  }
}

// ====== layer-2 deferred-projection aggregate: gather out1, 4 heads at once ====
// agg[n, h*256 + c] = (1/d_nh) * sum_j exp(e_j^h) * out1[src_j, c]
// Gather reads 512 B/edge (vs 1024 for h2); out1 table is 4MB = L2-resident.
__global__ __launch_bounds__(128) void gat_agg(
    const __hip_bfloat16* __restrict__ feat,   // out1 [L,256]
    const float* __restrict__ a_sd,            // a_sd2 [L,8]
    const int* __restrict__ row_start, const int* __restrict__ csr_src,
    __hip_bfloat16* __restrict__ agg) {        // [L, 1024]
  constexpr int BATCH = 8;
  int wid = threadIdx.x >> 6, lane = threadIdx.x & 63;
  int n = blockIdx.x * 2 + wid;
  int c0 = lane * 4;
  int rs = row_start[n], re = row_start[n + 1];
  float4 ad4 = *(const float4*)&a_sd[(size_t)n * 8 + 4];

  __shared__ __align__(16) uint2 s_m[2][64][4];   // masks for all 4 heads (4KB)
  float dp[4] = {0.f, 0.f, 0.f, 0.f};
  float acc[4][4] = {};                            // [head][channel]
  const unsigned short* hbase = (const unsigned short*)feat;

  int base = rs;
  int cnt = min(64, re - rs);
  int srcv = 0;
  float4 as4 = {0.f, 0.f, 0.f, 0.f};
  if (lane < cnt) {
    srcv = csr_src[rs + lane];
    as4 = *(const float4*)&a_sd[(size_t)srcv * 8];
  }

  while (base < re) {
    float w0 = 0.f, w1 = 0.f, w2 = 0.f, w3 = 0.f;
    if (lane < cnt) {
      w0 = __expf(lrelu(as4.x + ad4.x));
      w1 = __expf(lrelu(as4.y + ad4.y));
      w2 = __expf(lrelu(as4.z + ad4.z));
      w3 = __expf(lrelu(as4.w + ad4.w));
    }
    dp[0] += w0; dp[1] += w1; dp[2] += w2; dp[3] += w3;
    unsigned l0 = f2b(w0), l1 = f2b(w1), l2 = f2b(w2), l3 = f2b(w3);
    uint4 ma = {l0, l0 << 16, l1, l1 << 16};
    uint4 mb = {l2, l2 << 16, l3, l3 << 16};
    *(uint4*)&s_m[wid][lane][0] = ma;
    *(uint4*)&s_m[wid][lane][2] = mb;
    asm volatile("s_waitcnt lgkmcnt(0)" ::: "memory");
    int cur_src = srcv;
    int cur_cnt = cnt;
    int nbase = base + 64;
    bool have_next = nbase < re;
    cnt = min(64, re - nbase);
    srcv = 0;
    if (have_next && lane < cnt) srcv = csr_src[nbase + lane];
    float4 nas4 = {0.f, 0.f, 0.f, 0.f};
    bool did_asd = false;

    int j = 0;
    for (; j + BATCH <= cur_cnt; j += BATCH) {
      int srs[BATCH];
#pragma unroll
      for (int k = 0; k < BATCH; k++) srs[k] = __builtin_amdgcn_readlane(cur_src, j + k);
      uint2 hv[BATCH];
#pragma unroll
      for (int k = 0; k < BATCH; k++)
        hv[k] = *(const uint2*)&hbase[(size_t)srs[k] * 256 + c0];
      if (j == 0 && have_next) {
        if (lane < cnt) nas4 = *(const float4*)&a_sd[(size_t)srcv * 8];
        did_asd = true;
      }
#pragma unroll
      for (int k = 0; k < BATCH; k++) {
        uint4 mA = *(const uint4*)&s_m[wid][j + k][0];
        uint4 mB = *(const uint4*)&s_m[wid][j + k][2];
        unsigned hp[2] = {hv[k].x, hv[k].y};
        edge_fma<2>(hp, uint2{mA.x, mA.y}, acc[0]);
        edge_fma<2>(hp, uint2{mA.z, mA.w}, acc[1]);
        edge_fma<2>(hp, uint2{mB.x, mB.y}, acc[2]);
        edge_fma<2>(hp, uint2{mB.z, mB.w}, acc[3]);
      }
    }
    if (have_next && !did_asd && lane < cnt)
      nas4 = *(const float4*)&a_sd[(size_t)srcv * 8];
    for (; j < cur_cnt; j++) {
      int sr = __builtin_amdgcn_readlane(cur_src, j);
      uint2 hvv = *(const uint2*)&hbase[(size_t)sr * 256 + c0];
      uint4 mA = *(const uint4*)&s_m[wid][j][0];
      uint4 mB = *(const uint4*)&s_m[wid][j][2];
      unsigned hp[2] = {hvv.x, hvv.y};
      edge_fma<2>(hp, uint2{mA.x, mA.y}, acc[0]);
      edge_fma<2>(hp, uint2{mA.z, mA.w}, acc[1]);
      edge_fma<2>(hp, uint2{mB.x, mB.y}, acc[2]);
      edge_fma<2>(hp, uint2{mB.z, mB.w}, acc[3]);
    }
    as4 = nas4;
    base = nbase;
  }

#pragma unroll
  for (int off = 32; off > 0; off >>= 1) {
#pragma unroll
    for (int h = 0; h < 4; h++) dp[h] += __shfl_xor(dp[h], off);
  }
  unsigned short* op = (unsigned short*)agg + (size_t)n * 1024 + c0;
#pragma unroll
  for (int h = 0; h < 4; h++) {
    float inv = 1.f / (dp[h] + 1e-16f);
    ushort4 ov = {f2b(acc[h][0] * inv), f2b(acc[h][1] * inv),
                  f2b(acc[h][2] * inv), f2b(acc[h][3] * inv)};
    *(ushort4*)(op + h * 256) = ov;
  }
}

// ================= FC head (pre-transposed f32 weights) =================
__global__ __launch_bounds__(256) void fc1(const float* __restrict__ pooled,
                                           const float* __restrict__ Wt,
                                           const float* __restrict__ b,
                                           float* __restrict__ out) {
  __shared__ float pv[512];
  __shared__ float red[256];
  int t = threadIdx.x;
  pv[t] = pooled[t]; pv[t + 256] = pooled[t + 256];
  __syncthreads();
  int ol = t >> 4;
  int o = blockIdx.x * 16 + ol;
  int ks = (t & 15) * 32;
  float p = 0.f;
  const float* wr = &Wt[(size_t)o * 512 + ks];
#pragma unroll
  for (int kk = 0; kk < 32; kk++) p = fmaf(pv[ks + kk], wr[kk], p);
  red[t] = p;
  __syncthreads();
  if ((t & 15) == 0) {
    float s2 = 0.f;
#pragma unroll
    for (int i = 0; i < 16; i++) s2 += red[ol * 16 + i];
    out[o] = fmaxf(s2 + b[o], 0.f);
  }
}

__global__ __launch_bounds__(256) void fc2(const float* __restrict__ h,
                                           const float* __restrict__ Wt,
                                           const float* __restrict__ outb,
                                           float* __restrict__ out) {
  __shared__ float pv[512];
  __shared__ float red[256];
  int t = threadIdx.x;
  pv[t] = h[t]; pv[t + 256] = h[t + 256];
  __syncthreads();
  int ol = t >> 4;
  int o = blockIdx.x * 16 + ol;
  int ks = (t & 15) * 32;
  float p = 0.f;
  const float* wr = &Wt[(size_t)o * 512 + ks];
#pragma unroll
  for (int kk = 0; kk < 32; kk++) p = fmaf(pv[ks + kk], wr[kk], p);
  red[t] = p;
  __syncthreads();
  if ((t & 15) == 0 && o < 489) {
    float s2 = 0.f;
#pragma unroll
    for (int i = 0; i < 16; i++) s2 += red[ol * 16 + i];
    out[o] = s2 + outb[o];
  }
}

extern "C" void kernel_launch(void* const* d_in, const int* in_sizes, int n_in,
                              void* d_out, int out_size, void* d_ws, size_t ws_size,
                              hipStream_t stream) {
  const float* seq   = (const float*)d_in[0];
  const int*   ei    = (const int*)d_in[1];
  const float* W1    = (const float*)d_in[2];
  const float* W2    = (const float*)d_in[3];
  const float* Wg1   = (const float*)d_in[4];
  const float* asrc1 = (const float*)d_in[5];
  const float* adst1 = (const float*)d_in[6];
  const float* b1    = (const float*)d_in[7];
  const float* Wg2   = (const float*)d_in[8];
  const float* asrc2 = (const float*)d_in[9];
  const float* adst2 = (const float*)d_in[10];
  const float* b2    = (const float*)d_in[11];
  const float* fcW   = (const float*)d_in[12];
  const float* fcb   = (const float*)d_in[13];
  const float* outW  = (const float*)d_in[14];
  const float* outb  = (const float*)d_in[15];
  float* outp = (float*)d_out;

  const int E = in_sizes[1] / 2;      // 524288
  const int Etot = E + L;             // + self loops

  // ---- workspace layout ----
  char* ws = (char*)d_ws;
  __hip_bfloat16* mlp1 = (__hip_bfloat16*)(ws + 0);           // [L,1024] 16MB (dead after x0 GEMM)
  __hip_bfloat16* agg2 = (__hip_bfloat16*)(ws + 0);           // [L,1024] 16MB (after mlp1 dead)
  __hip_bfloat16* x0   = (__hip_bfloat16*)(ws + (24u << 20)); // [L,256] 4MB
  __hip_bfloat16* h1   = (__hip_bfloat16*)(ws + (28u << 20)); // [L,256] 4MB
  __hip_bfloat16* out1 = (__hip_bfloat16*)(ws + (32u << 20)); // [L,256] 4MB
  size_t off = (36u << 20);
  __hip_bfloat16* xb   = (__hip_bfloat16*)(ws + off); off += (size_t)L * 32 * 2;
  __hip_bfloat16* W1t  = (__hip_bfloat16*)(ws + off); off += (size_t)1024 * 32 * 2;
  __hip_bfloat16* W2t  = (__hip_bfloat16*)(ws + off); off += (size_t)256 * 1024 * 2;
  __hip_bfloat16* Wg1t = (__hip_bfloat16*)(ws + off); off += (size_t)320 * 256 * 2;  // extended
  __hip_bfloat16* Wg2t = (__hip_bfloat16*)(ws + off); off += (size_t)512 * 256 * 2;
  float* fcWt  = (float*)(ws + off); off += (size_t)512 * 512 * 4;
  float* outWt = (float*)(ws + off); off += (size_t)512 * 512 * 4;
  int* csr_src = (int*)(ws + off); off += (size_t)Etot * 4;
  int* rank    = (int*)(ws + off); off += (size_t)Etot * 4;
  off = (off + 255) & ~(size_t)255;
  int* row_start = (int*)(ws + off); off += (size_t)(L + 1) * 4;
  off = (off + 255) & ~(size_t)255;
  int* deg    = (int*)(ws + off); off += (size_t)L * 4;
  float* a_sd1 = (float*)(ws + off); off += (size_t)L * 8 * 4;
  float* a_sd2 = (float*)(ws + off); off += (size_t)L * 8 * 4;
  float* wa2 = (float*)(ws + off); off += 2048 * 4;
  float* pooled = (float*)(ws + off); off += 512 * 4;
  float* hbuf   = (float*)(ws + off); off += 512 * 4;

  // ---- zero deg ----
  hipMemsetAsync(deg, 0, (size_t)L * 4, stream);

  // ---- merged transposes + conversions + wa + degree/rank ----
  int convN = 262144 + 2048 + 2048 + 14336 + Etot;
  int convB = (convN + 255) / 256;
  conv_combo<<<992 + convB, 256, 0, stream>>>(
      seq, W1, W2, Wg1, Wg2, fcW, outW, ei, asrc1, adst1, asrc2, adst2, E, Etot,
      xb, W1t, W2t, Wg1t, Wg2t, fcWt, outWt, wa2, deg, rank);

  // ---- CSR ----
  scan_deg<<<1, 1024, 0, stream>>>(deg, row_start, pooled);
  scatter_edges<<<(Etot + 255) / 256, 256, 0, stream>>>(ei, E, Etot, row_start, rank, csr_src);

  // ---- input MLP ----
  gemm_big<32, true, false><<<dim3(16, 64), 256, 0, stream>>>(xb, W1t, mlp1, nullptr, L, 1024, 32);
  gemm_big<64, false, false><<<dim3(4, 64), 256, 0, stream>>>(mlp1, W2t, x0, nullptr, L, 256, 1024);

  // ---- GAT layer 1 (C=64): h1 GEMM also emits a_sd1 via extended Wg1t ----
  gemm_big<64, false, true><<<dim3(5, 64), 256, 0, stream>>>(x0, Wg1t, h1, a_sd1, L, 256, 256);
  gat_fused<64, true><<<4096, 128, 0, stream>>>(h1, a_sd1, row_start, csr_src, b1, out1, wa2, a_sd2);

  // ---- GAT layer 2: aggregate out1 (deferred projection), then per-head GEMM
  //      with fused bias+ReLU+column-sum into pooled ----
  gat_agg<<<4096, 128, 0, stream>>>(out1, a_sd2, row_start, csr_src, agg2);
  gemm_head<<<dim3(2, 64, 4), 256, 0, stream>>>(agg2, Wg2t, b2, pooled);

  // ---- FC head ----
  fc1<<<32, 256, 0, stream>>>(pooled, fcWt, fcb, hbuf);
  fc2<<<31, 256, 0, stream>>>(hbuf, outWt, outb, outp);
}

// Round 13
// 181.427 us; speedup vs baseline: 1.2411x; 1.0154x over previous
//
#include <hip/hip_runtime.h>
#include <hip/hip_bf16.h>

constexpr int L = 8192;          // nodes
constexpr int H = 4;             // heads (both layers)

typedef __attribute__((ext_vector_type(8))) short bf16x8;
typedef __attribute__((ext_vector_type(8))) unsigned short u16x8;
typedef __attribute__((ext_vector_type(4))) float f32x4;

#if defined(__has_builtin)
#  if __has_builtin(__builtin_amdgcn_fdot2_f32_bf16)
#    define HAVE_DOT2 1
#  endif
#endif
#ifndef HAVE_DOT2
#  define HAVE_DOT2 0
#endif
#if HAVE_DOT2
typedef __attribute__((ext_vector_type(2))) __bf16 bfx2;
#endif

static __device__ __forceinline__ float lrelu(float e) {
  return e > 0.f ? e : 0.2f * e;
}
static __device__ __forceinline__ float b2f(unsigned short s) {
  return __uint_as_float(((unsigned)s) << 16);
}
static __device__ __forceinline__ unsigned short f2b(float f) {
  __hip_bfloat16 h = __float2bfloat16(f);
  return *reinterpret_cast<unsigned short*>(&h);
}

// per-edge channel-pair accumulate: hv[p] holds channels (2p,2p+1) as packed
// bf16; m.x = (alpha,0), m.y = (0,alpha) packed bf16 masks.
template<int PAIRS>
static __device__ __forceinline__ void edge_fma(const unsigned* hv, uint2 m, float* acc) {
#if HAVE_DOT2
#pragma unroll
  for (int p = 0; p < PAIRS; p++) {
    acc[2 * p]     = __builtin_amdgcn_fdot2_f32_bf16(
        __builtin_bit_cast(bfx2, hv[p]), __builtin_bit_cast(bfx2, m.x), acc[2 * p], false);
    acc[2 * p + 1] = __builtin_amdgcn_fdot2_f32_bf16(
        __builtin_bit_cast(bfx2, hv[p]), __builtin_bit_cast(bfx2, m.y), acc[2 * p + 1], false);
  }
#else
  float af = b2f((unsigned short)(m.x & 0xffffu));
#pragma unroll
  for (int p = 0; p < PAIRS; p++) {
    acc[2 * p]     = fmaf(af, b2f((unsigned short)(hv[p] & 0xffffu)), acc[2 * p]);
    acc[2 * p + 1] = fmaf(af, b2f((unsigned short)(hv[p] >> 16)), acc[2 * p + 1]);
  }
#endif
}

// ========== merged: LDS-tiled transposes (blocks 0..991) + elementwise tail ====
// tail blocks (bb = blockIdx.x - 992):
//   [0,1024)        xb conversion (262144 elems)
//   [1024,1536)     wa1 -> Wg1t ext rows, wave-parallel (2048 outputs, 4/block)
//   [1536,2048)     wa2 f32, wave-parallel (2048 outputs, 4/block)
//   [2048,2104)     Wg1t zero rows (14336 elems)
//   [2104,...)      deg/rank atomic count (Etot elems)
__global__ __launch_bounds__(256) void conv_combo(
    const float* __restrict__ seq, const float* __restrict__ W1,
    const float* __restrict__ W2, const float* __restrict__ Wg1,
    const float* __restrict__ Wg2, const float* __restrict__ fcW,
    const float* __restrict__ outW, const int* __restrict__ ei,
    const float* __restrict__ as1, const float* __restrict__ ad1,
    const float* __restrict__ as2, const float* __restrict__ ad2,
    int E, int Etot,
    __hip_bfloat16* __restrict__ xb, __hip_bfloat16* __restrict__ W1t,
    __hip_bfloat16* __restrict__ W2t, __hip_bfloat16* __restrict__ Wg1t,
    __hip_bfloat16* __restrict__ Wg2t, float* __restrict__ fcWt,
    float* __restrict__ outWt, float* __restrict__ wa2,
    int* __restrict__ deg, int* __restrict__ rank) {
  __shared__ float tile[32][33];
  int t = threadIdx.x;
  if (blockIdx.x < 992) {
    int b = blockIdx.x;
    const float* src; void* dst; bool obf16; int K, N, Kout, kt, nt;
    if (b < 256)               { src = W2;  dst = W2t;  obf16 = true;  K = 1024; N = 256; Kout = 1024; nt = b & 7;  kt = b >> 3; }
    else if ((b -= 256) < 64)  { src = Wg1; dst = Wg1t; obf16 = true;  K = 256;  N = 256; Kout = 256;  nt = b & 7;  kt = b >> 3; }
    else if ((b -= 64) < 128)  { src = Wg2; dst = Wg2t; obf16 = true;  K = 256;  N = 512; Kout = 256;  nt = b & 15; kt = b >> 4; }
    else if ((b -= 128) < 256) { src = fcW; dst = fcWt; obf16 = false; K = 512;  N = 512; Kout = 512;  nt = b & 15; kt = b >> 4; }
    else if ((b -= 256) < 256) { src = outW;dst = outWt;obf16 = false; K = 512;  N = 489; Kout = 512;  nt = b & 15; kt = b >> 4; }
    else { b -= 256;             src = W1;  dst = W1t;  obf16 = true;  K = 26;   N = 1024;Kout = 32;   nt = b;      kt = 0; }
    int lr = t >> 3, lc4 = (t & 7) * 4;
    int gk = kt * 32 + lr, gn = nt * 32 + lc4;
    float4 v = {0.f, 0.f, 0.f, 0.f};
    if (gk < K) {
      const float* p = &src[(size_t)gk * N + gn];
      v.x = (gn + 0 < N) ? p[0] : 0.f;
      v.y = (gn + 1 < N) ? p[1] : 0.f;
      v.z = (gn + 2 < N) ? p[2] : 0.f;
      v.w = (gn + 3 < N) ? p[3] : 0.f;
    }
    tile[lr][lc4 + 0] = v.x; tile[lr][lc4 + 1] = v.y;
    tile[lr][lc4 + 2] = v.z; tile[lr][lc4 + 3] = v.w;
    __syncthreads();
    int on = nt * 32 + lr, ok = kt * 32 + lc4;
    if (on >= N || ok >= Kout) return;
    float o0 = tile[lc4 + 0][lr], o1 = tile[lc4 + 1][lr];
    float o2 = tile[lc4 + 2][lr], o3 = tile[lc4 + 3][lr];
    if (obf16) {
      ushort4 u = {f2b(o0), f2b(o1), f2b(o2), f2b(o3)};
      *(ushort4*)&((__hip_bfloat16*)dst)[(size_t)on * Kout + ok] = u;
    } else {
      float4 u = {o0, o1, o2, o3};
      *(float4*)&((float*)dst)[(size_t)on * Kout + ok] = u;
    }
    return;
  }
  int bb = blockIdx.x - 992;
  if (bb < 1024) {
    int i = bb * 256 + t;
    int r = i >> 5, k = i & 31;
    xb[i] = __float2bfloat16(k < 26 ? seq[r * 26 + k] : 0.f);
    return;
  }
  bb -= 1024;
  int lane = t & 63, wid = t >> 6;
  if (bb < 512) {  // wa1, wave-parallel: 64-length dot per output
    int idx = bb * 4 + wid;             // 0..2047
    int k = idx >> 3, o = idx & 7, h = o & 3;
    const float* av = (o < 4) ? as1 : ad1;
    float v = Wg1[k * 256 + h * 64 + lane] * av[h * 64 + lane];
#pragma unroll
    for (int off = 32; off > 0; off >>= 1) v += __shfl_xor(v, off);
    if (lane == 0) Wg1t[(size_t)(256 + o) * 256 + k] = __float2bfloat16(v);
    return;
  }
  bb -= 512;
  if (bb < 512) {  // wa2, wave-parallel: 128-length dot per output
    int idx = bb * 4 + wid;             // 0..2047
    int k = idx >> 3, o = idx & 7, h = o & 3;
    const float* av = (o < 4) ? as2 : ad2;
    float v = Wg2[k * 512 + h * 128 + lane] * av[h * 128 + lane]
            + Wg2[k * 512 + h * 128 + 64 + lane] * av[h * 128 + 64 + lane];
#pragma unroll
    for (int off = 32; off > 0; off >>= 1) v += __shfl_xor(v, off);
    if (lane == 0) wa2[idx] = v;
    return;
  }
  bb -= 512;
  if (bb < 56) {   // Wg1t zero rows 264..319 (14336 bf16)
    int i = bb * 256 + t;
    ((__hip_bfloat16*)Wg1t)[(size_t)264 * 256 + i] = __float2bfloat16(0.f);
    return;
  }
  bb -= 56;
  int e = bb * 256 + t;
  if (e < Etot) {
    int dst = (e < E) ? ei[E + e] : (e - E);
    rank[e] = atomicAdd(&deg[dst], 1);
  }
}

// ============ bf16 MFMA GEMM: C = op(A[M,K] @ Bt[*,K]^T), 128x64 tile =========
template<int BK, bool RELU, bool ASD>
__global__ __launch_bounds__(256) void gemm_big(
    const __hip_bfloat16* __restrict__ A, const __hip_bfloat16* __restrict__ Bt,
    __hip_bfloat16* __restrict__ C, float* __restrict__ asd,
    int M, int N, int K) {
  __shared__ __align__(16) short As[128][BK + 8];
  __shared__ __align__(16) short Bs[64][BK + 8];
  int tid = threadIdx.x;
  int m0 = blockIdx.y * 128, n0 = blockIdx.x * 64;
  int w = tid >> 6, lane = tid & 63;
  int wm = (w >> 1) * 64, wn = (w & 1) * 32;
  f32x4 acc[4][2] = {};
  for (int k0 = 0; k0 < K; k0 += BK) {
    if constexpr (BK == 64) {
#pragma unroll
      for (int i = 0; i < 4; i++) {
        int ch = i * 256 + tid; int r = ch >> 3, kg = ch & 7;
        *(bf16x8*)&As[r][kg * 8] = *(const bf16x8*)&A[(size_t)(m0 + r) * K + k0 + kg * 8];
      }
#pragma unroll
      for (int i = 0; i < 2; i++) {
        int ch = i * 256 + tid; int r = ch >> 3, kg = ch & 7;
        *(bf16x8*)&Bs[r][kg * 8] = *(const bf16x8*)&Bt[(size_t)(n0 + r) * K + k0 + kg * 8];
      }
    } else {  // BK == 32
#pragma unroll
      for (int i = 0; i < 2; i++) {
        int ch = i * 256 + tid; int r = ch >> 2, kg = ch & 3;
        *(bf16x8*)&As[r][kg * 8] = *(const bf16x8*)&A[(size_t)(m0 + r) * K + k0 + kg * 8];
      }
      { int r = tid >> 2, kg = tid & 3;
        *(bf16x8*)&Bs[r][kg * 8] = *(const bf16x8*)&Bt[(size_t)(n0 + r) * K + k0 + kg * 8]; }
    }
    __syncthreads();
    int kk = (lane >> 4) * 8;
#pragma unroll
    for (int ks = 0; ks < BK / 32; ks++) {
      bf16x8 af[4], bfr[2];
#pragma unroll
      for (int m = 0; m < 4; m++)
        af[m] = *(const bf16x8*)&As[wm + m * 16 + (lane & 15)][ks * 32 + kk];
#pragma unroll
      for (int n = 0; n < 2; n++)
        bfr[n] = *(const bf16x8*)&Bs[wn + n * 16 + (lane & 15)][ks * 32 + kk];
#pragma unroll
      for (int m = 0; m < 4; m++)
#pragma unroll
        for (int n = 0; n < 2; n++)
          acc[m][n] = __builtin_amdgcn_mfma_f32_16x16x32_bf16(af[m], bfr[n], acc[m][n], 0, 0, 0);
    }
    __syncthreads();
  }
#pragma unroll
  for (int m = 0; m < 4; m++) {
#pragma unroll
    for (int n = 0; n < 2; n++) {
      int col = n0 + wn + n * 16 + (lane & 15);
#pragma unroll
      for (int j = 0; j < 4; j++) {
        int row = m0 + wm + m * 16 + (lane >> 4) * 4 + j;
        float v = acc[m][n][j];
        if (RELU) v = fmaxf(v, 0.f);
        if (!ASD) {
          C[(size_t)row * N + col] = __float2bfloat16(v);
        } else {
          if (col < N) C[(size_t)row * N + col] = __float2bfloat16(v);
          else if (col < N + 8) asd[(size_t)row * 8 + (col - N)] = v;
        }
      }
    }
  }
}

// ====== per-head batched GEMM over agg2, fused bias+ReLU+column-sum ============
__global__ __launch_bounds__(256) void gemm_head(
    const __hip_bfloat16* __restrict__ agg,   // [L, 4*256], head z at col z*256
    const __hip_bfloat16* __restrict__ Wg2t,  // [512, 256]; head z rows z*128..
    const float* __restrict__ b2,             // [512]
    float* __restrict__ pooled) {             // [512]
  constexpr int BK = 64;
  __shared__ __align__(16) short As[128][BK + 8];
  __shared__ __align__(16) short Bs[64][BK + 8];
  __shared__ float s_cs[4][32];
  int tid = threadIdx.x;
  int z = blockIdx.z;
  int m0 = blockIdx.y * 128, n0 = blockIdx.x * 64;   // n0 within head's 128
  const __hip_bfloat16* A = agg + (size_t)z * 256;
  const __hip_bfloat16* Bt = Wg2t + (size_t)z * 128 * 256;
  int w = tid >> 6, lane = tid & 63;
  int wm = (w >> 1) * 64, wn = (w & 1) * 32;
  f32x4 acc[4][2] = {};
  for (int k0 = 0; k0 < 256; k0 += BK) {
#pragma unroll
    for (int i = 0; i < 4; i++) {
      int ch = i * 256 + tid; int r = ch >> 3, kg = ch & 7;
      *(bf16x8*)&As[r][kg * 8] = *(const bf16x8*)&A[(size_t)(m0 + r) * 1024 + k0 + kg * 8];
    }
#pragma unroll
    for (int i = 0; i < 2; i++) {
      int ch = i * 256 + tid; int r = ch >> 3, kg = ch & 7;
      *(bf16x8*)&Bs[r][kg * 8] = *(const bf16x8*)&Bt[(size_t)(n0 + r) * 256 + k0 + kg * 8];
    }
    __syncthreads();
    int kk = (lane >> 4) * 8;
#pragma unroll
    for (int ks = 0; ks < BK / 32; ks++) {
      bf16x8 af[4], bfr[2];
#pragma unroll
      for (int m = 0; m < 4; m++)
        af[m] = *(const bf16x8*)&As[wm + m * 16 + (lane & 15)][ks * 32 + kk];
#pragma unroll
      for (int n = 0; n < 2; n++)
        bfr[n] = *(const bf16x8*)&Bs[wn + n * 16 + (lane & 15)][ks * 32 + kk];
#pragma unroll
      for (int m = 0; m < 4; m++)
#pragma unroll
        for (int n = 0; n < 2; n++)
          acc[m][n] = __builtin_amdgcn_mfma_f32_16x16x32_bf16(af[m], bfr[n], acc[m][n], 0, 0, 0);
    }
    __syncthreads();
  }
  float cs[2] = {0.f, 0.f};
#pragma unroll
  for (int n = 0; n < 2; n++) {
    float bv = b2[z * 128 + n0 + wn + n * 16 + (lane & 15)];
#pragma unroll
    for (int m = 0; m < 4; m++)
#pragma unroll
      for (int j = 0; j < 4; j++)
        cs[n] += fmaxf(acc[m][n][j] + bv, 0.f);
  }
#pragma unroll
  for (int n = 0; n < 2; n++) {
    cs[n] += __shfl_xor(cs[n], 16);
    cs[n] += __shfl_xor(cs[n], 32);
  }
  if (lane < 16) { s_cs[w][lane] = cs[0]; s_cs[w][16 + lane] = cs[1]; }
  __syncthreads();
  if (tid < 64) {
    int c = tid;
    int bsel = c >> 5;
    float s = s_cs[bsel][c & 31] + s_cs[bsel + 2][c & 31];
    atomicAdd(&pooled[z * 128 + n0 + c], s);
  }
}

// ================= CSR build: shuffle-based scan (1 barrier) =================
__global__ __launch_bounds__(1024) void scan_deg(const int* __restrict__ deg,
                                                 int* __restrict__ row_start,
                                                 float* __restrict__ pooled) {
  __shared__ int wsum[16];
  int t = threadIdx.x;
  if (t < 512) pooled[t] = 0.f;
  int lane = t & 63, w = t >> 6;
  int local[8];
  int sum = 0;
#pragma unroll
  for (int j = 0; j < 8; j++) { local[j] = deg[t * 8 + j]; sum += local[j]; }
  int v = sum;
#pragma unroll
  for (int off = 1; off < 64; off <<= 1) {
    int u = __shfl_up(v, off);
    if (lane >= off) v += u;
  }
  if (lane == 63) wsum[w] = v;
  __syncthreads();
  int woff = 0;
  for (int i = 0; i < w; i++) woff += wsum[i];
  int base = woff + v - sum;   // exclusive prefix
#pragma unroll
  for (int j = 0; j < 8; j++) { row_start[t * 8 + j] = base; base += local[j]; }
  if (t == 1023) row_start[L] = base;
}

// atomic-free scatter using precomputed ranks
__global__ void scatter_edges(const int* __restrict__ ei, int E, int Etot,
                              const int* __restrict__ row_start,
                              const int* __restrict__ rank, int* __restrict__ csr_src) {
  int e = blockIdx.x * blockDim.x + threadIdx.x;
  if (e >= Etot) return;
  int srcv, dstv;
  if (e < E) { srcv = ei[e]; dstv = ei[E + e]; } else { srcv = dstv = e - E; }
  csr_src[row_start[dstv] + rank[e]] = srcv;
}

// ====== layer-1 fused softmax+aggregate (2 nodes/block) ====
template<int C, bool ASD2>
__global__ __launch_bounds__(128) void gat_fused(
    const __hip_bfloat16* __restrict__ hfeat, const float* __restrict__ a_sd,
    const int* __restrict__ row_start, const int* __restrict__ csr_src,
    const float* __restrict__ bias, __hip_bfloat16* __restrict__ out,
    const float* __restrict__ wa2, float* __restrict__ a_sd2) {
  constexpr int HC = 4 * C;
  constexpr int VEC = HC / 64;            // 4
  constexpr int PAIRS = VEC / 2;          // 2
  constexpr int BATCH = 12;               // in-flight 8B row gathers
  int wid = threadIdx.x >> 6, lane = threadIdx.x & 63;
  int n = blockIdx.x * 2 + wid;
  int c0 = lane * VEC;
  int hl = (c0 / C) & 3;
  int rs = row_start[n], re = row_start[n + 1];
  float4 ad4 = *(const float4*)&a_sd[(size_t)n * 8 + 4];

  __shared__ __align__(16) uint2 s_m[2][64][4];   // expanded alpha masks (4KB)
  float dp[4] = {0.f, 0.f, 0.f, 0.f};
  float acc[VEC] = {};
  const unsigned short* hbase = (const unsigned short*)hfeat;

  int base = rs;
  int cnt = min(64, re - rs);
  int srcv = 0;
  float4 as4 = {0.f, 0.f, 0.f, 0.f};
  if (lane < cnt) {
    srcv = csr_src[rs + lane];
    as4 = *(const float4*)&a_sd[(size_t)srcv * 8];
  }

  while (base < re) {
    float w0 = 0.f, w1 = 0.f, w2 = 0.f, w3 = 0.f;
    if (lane < cnt) {
      w0 = __expf(lrelu(as4.x + ad4.x));
      w1 = __expf(lrelu(as4.y + ad4.y));
      w2 = __expf(lrelu(as4.z + ad4.z));
      w3 = __expf(lrelu(as4.w + ad4.w));
    }
    dp[0] += w0; dp[1] += w1; dp[2] += w2; dp[3] += w3;
    unsigned l0 = f2b(w0), l1 = f2b(w1), l2 = f2b(w2), l3 = f2b(w3);
    uint4 ma = {l0, l0 << 16, l1, l1 << 16};
    uint4 mb = {l2, l2 << 16, l3, l3 << 16};
    *(uint4*)&s_m[wid][lane][0] = ma;
    *(uint4*)&s_m[wid][lane][2] = mb;
    asm volatile("s_waitcnt lgkmcnt(0)" ::: "memory");
    int cur_src = srcv;
    int cur_cnt = cnt;
    int nbase = base + 64;
    bool have_next = nbase < re;
    cnt = min(64, re - nbase);
    srcv = 0;
    if (have_next && lane < cnt) srcv = csr_src[nbase + lane];
    float4 nas4 = {0.f, 0.f, 0.f, 0.f};
    bool did_asd = false;

    int j = 0;
    for (; j + BATCH <= cur_cnt; j += BATCH) {
      int srs[BATCH];
#pragma unroll
      for (int k = 0; k < BATCH; k++) srs[k] = __builtin_amdgcn_readlane(cur_src, j + k);
      unsigned hv[BATCH][PAIRS];
#pragma unroll
      for (int k = 0; k < BATCH; k++) {
        const unsigned short* hp = &hbase[(size_t)srs[k] * HC + c0];
        *(uint2*)&hv[k][0] = *(const uint2*)hp;
      }
      if (j == 0 && have_next) {
        if (lane < cnt) nas4 = *(const float4*)&a_sd[(size_t)srcv * 8];
        did_asd = true;
      }
#pragma unroll
      for (int k = 0; k < BATCH; k++) {
        uint2 m = s_m[wid][j + k][hl];
        edge_fma<PAIRS>(hv[k], m, acc);
      }
    }
    if (have_next && !did_asd && lane < cnt)
      nas4 = *(const float4*)&a_sd[(size_t)srcv * 8];
    for (; j < cur_cnt; j++) {
      int sr = __builtin_amdgcn_readlane(cur_src, j);
      unsigned hv[PAIRS];
      const unsigned short* hp = &hbase[(size_t)sr * HC + c0];
      *(uint2*)&hv[0] = *(const uint2*)hp;
      uint2 m = s_m[wid][j][hl];
      edge_fma<PAIRS>(hv, m, acc);
    }
    as4 = nas4;
    base = nbase;
  }

#pragma unroll
  for (int off = 32; off > 0; off >>= 1) {
#pragma unroll
    for (int h = 0; h < 4; h++) dp[h] += __shfl_xor(dp[h], off);
  }
  float dsel = hl == 0 ? dp[0] : hl == 1 ? dp[1] : hl == 2 ? dp[2] : dp[3];
  float inv = 1.f / (dsel + 1e-16f);

#pragma unroll
  for (int k = 0; k < VEC; k++)
    acc[k] = fmaxf(fmaf(acc[k], inv, bias[c0 + k]), 0.f);
  unsigned short* op = (unsigned short*)out + (size_t)n * HC + c0;
  ushort4 ov = {f2b(acc[0]), f2b(acc[1]), f2b(acc[2]), f2b(acc[3])};
  *(ushort4*)op = ov;

  if constexpr (ASD2) {
    float p[8] = {};
#pragma unroll
    for (int q = 0; q < VEC; q++) {
      const float* wr = &wa2[(size_t)(c0 + q) * 8];
#pragma unroll
      for (int o = 0; o < 8; o++) p[o] = fmaf(acc[q], wr[o], p[o]);
    }
#pragma unroll
    for (int off = 32; off > 0; off >>= 1) {
#pragma unroll
      for (int o = 0; o < 8; o++) p[o] += __shfl_xor(p[o], off);
    }
    if (lane == 0) {
      float4 p0 = {p[0], p[1], p[2], p[3]};
      float4 p1 = {p[4], p[5], p[6], p[7]};
      *(float4*)&a_sd2[(size_t)n * 8 + 0] = p0;
      *(float4*)&a_sd2[(size_t)n * 8 + 4] = p1;
    }
  }
}

// ====== layer-2 deferred-projection aggregate: gather out1, 4 heads at once ====
__global__ __launch_bounds__(128) void gat_agg(
    const __hip_bfloat16* __restrict__ feat,   // out1 [L,256]
    const float* __restrict__ a_sd,            // a_sd2 [L,8]
    const int* __restrict__ row_start, const int* __restrict__ csr_src,
    __hip_bfloat16* __restrict__ agg) {        // [L, 1024]
  constexpr int BATCH = 8;
  int wid = threadIdx.x >> 6, lane = threadIdx.x & 63;
  int n = blockIdx.x * 2 + wid;
  int c0 = lane * 4;
  int rs = row_start[n], re = row_start[n + 1];
  float4 ad4 = *(const float4*)&a_sd[(size_t)n * 8 + 4];

  __shared__ __align__(16) uint2 s_m[2][64][4];   // masks for all 4 heads (4KB)
  float dp[4] = {0.f, 0.f, 0.f, 0.f};
  float acc[4][4] = {};                            // [head][channel]
  const unsigned short* hbase = (const unsigned short*)feat;

  int base = rs;
  int cnt = min(64, re - rs);
  int srcv = 0;
  float4 as4 = {0.f, 0.f, 0.f, 0.f};
  if (lane < cnt) {
    srcv = csr_src[rs + lane];
    as4 = *(const float4*)&a_sd[(size_t)srcv * 8];
  }

  while (base < re) {
    float w0 = 0.f, w1 = 0.f, w2 = 0.f, w3 = 0.f;
    if (lane < cnt) {
      w0 = __expf(lrelu(as4.x + ad4.x));
      w1 = __expf(lrelu(as4.y + ad4.y));
      w2 = __expf(lrelu(as4.z + ad4.z));
      w3 = __expf(lrelu(as4.w + ad4.w));
    }
    dp[0] += w0; dp[1] += w1; dp[2] += w2; dp[3] += w3;
    unsigned l0 = f2b(w0), l1 = f2b(w1), l2 = f2b(w2), l3 = f2b(w3);
    uint4 ma = {l0, l0 << 16, l1, l1 << 16};
    uint4 mb = {l2, l2 << 16, l3, l3 << 16};
    *(uint4*)&s_m[wid][lane][0] = ma;
    *(uint4*)&s_m[wid][lane][2] = mb;
    asm volatile("s_waitcnt lgkmcnt(0)" ::: "memory");
    int cur_src = srcv;
    int cur_cnt = cnt;
    int nbase = base + 64;
    bool have_next = nbase < re;
    cnt = min(64, re - nbase);
    srcv = 0;
    if (have_next && lane < cnt) srcv = csr_src[nbase + lane];
    float4 nas4 = {0.f, 0.f, 0.f, 0.f};
    bool did_asd = false;

    int j = 0;
    for (; j + BATCH <= cur_cnt; j += BATCH) {
      int srs[BATCH];
#pragma unroll
      for (int k = 0; k < BATCH; k++) srs[k] = __builtin_amdgcn_readlane(cur_src, j + k);
      uint2 hv[BATCH];
#pragma unroll
      for (int k = 0; k < BATCH; k++)
        hv[k] = *(const uint2*)&hbase[(size_t)srs[k] * 256 + c0];
      if (j == 0 && have_next) {
        if (lane < cnt) nas4 = *(const float4*)&a_sd[(size_t)srcv * 8];
        did_asd = true;
      }
#pragma unroll
      for (int k = 0; k < BATCH; k++) {
        uint4 mA = *(const uint4*)&s_m[wid][j + k][0];
        uint4 mB = *(const uint4*)&s_m[wid][j + k][2];
        unsigned hp[2] = {hv[k].x, hv[k].y};
        edge_fma<2>(hp, uint2{mA.x, mA.y}, acc[0]);
        edge_fma<2>(hp, uint2{mA.z, mA.w}, acc[1]);
        edge_fma<2>(hp, uint2{mB.x, mB.y}, acc[2]);
        edge_fma<2>(hp, uint2{mB.z, mB.w}, acc[3]);
      }
    }
    if (have_next && !did_asd && lane < cnt)
      nas4 = *(const float4*)&a_sd[(size_t)srcv * 8];
    for (; j < cur_cnt; j++) {
      int sr = __builtin_amdgcn_readlane(cur_src, j);
      uint2 hvv = *(const uint2*)&hbase[(size_t)sr * 256 + c0];
      uint4 mA = *(const uint4*)&s_m[wid][j][0];
      uint4 mB = *(const uint4*)&s_m[wid][j][2];
      unsigned hp[2] = {hvv.x, hvv.y};
      edge_fma<2>(hp, uint2{mA.x, mA.y}, acc[0]);
      edge_fma<2>(hp, uint2{mA.z, mA.w}, acc[1]);
      edge_fma<2>(hp, uint2{mB.x, mB.y}, acc[2]);
      edge_fma<2>(hp, uint2{mB.z, mB.w}, acc[3]);
    }
    as4 = nas4;
    base = nbase;
  }

#pragma unroll
  for (int off = 32; off > 0; off >>= 1) {
#pragma unroll
    for (int h = 0; h < 4; h++) dp[h] += __shfl_xor(dp[h], off);
  }
  unsigned short* op = (unsigned short*)agg + (size_t)n * 1024 + c0;
#pragma unroll
  for (int h = 0; h < 4; h++) {
    float inv = 1.f / (dp[h] + 1e-16f);
    ushort4 ov = {f2b(acc[h][0] * inv), f2b(acc[h][1] * inv),
                  f2b(acc[h][2] * inv), f2b(acc[h][3] * inv)};
    *(ushort4*)(op + h * 256) = ov;
  }
}

// ================= FC head (pre-transposed f32 weights) =================
__global__ __launch_bounds__(256) void fc1(const float* __restrict__ pooled,
                                           const float* __restrict__ Wt,
                                           const float* __restrict__ b,
                                           float* __restrict__ out) {
  __shared__ float pv[512];
  __shared__ float red[256];
  int t = threadIdx.x;
  pv[t] = pooled[t]; pv[t + 256] = pooled[t + 256];
  __syncthreads();
  int ol = t >> 4;
  int o = blockIdx.x * 16 + ol;
  int ks = (t & 15) * 32;
  float p = 0.f;
  const float* wr = &Wt[(size_t)o * 512 + ks];
#pragma unroll
  for (int kk = 0; kk < 32; kk++) p = fmaf(pv[ks + kk], wr[kk], p);
  red[t] = p;
  __syncthreads();
  if ((t & 15) == 0) {
    float s2 = 0.f;
#pragma unroll
    for (int i = 0; i < 16; i++) s2 += red[ol * 16 + i];
    out[o] = fmaxf(s2 + b[o], 0.f);
  }
}

__global__ __launch_bounds__(256) void fc2(const float* __restrict__ h,
                                           const float* __restrict__ Wt,
                                           const float* __restrict__ outb,
                                           float* __restrict__ out) {
  __shared__ float pv[512];
  __shared__ float red[256];
  int t = threadIdx.x;
  pv[t] = h[t]; pv[t + 256] = h[t + 256];
  __syncthreads();
  int ol = t >> 4;
  int o = blockIdx.x * 16 + ol;
  int ks = (t & 15) * 32;
  float p = 0.f;
  const float* wr = &Wt[(size_t)o * 512 + ks];
#pragma unroll
  for (int kk = 0; kk < 32; kk++) p = fmaf(pv[ks + kk], wr[kk], p);
  red[t] = p;
  __syncthreads();
  if ((t & 15) == 0 && o < 489) {
    float s2 = 0.f;
#pragma unroll
    for (int i = 0; i < 16; i++) s2 += red[ol * 16 + i];
    out[o] = s2 + outb[o];
  }
}

extern "C" void kernel_launch(void* const* d_in, const int* in_sizes, int n_in,
                              void* d_out, int out_size, void* d_ws, size_t ws_size,
                              hipStream_t stream) {
  const float* seq   = (const float*)d_in[0];
  const int*   ei    = (const int*)d_in[1];
  const float* W1    = (const float*)d_in[2];
  const float* W2    = (const float*)d_in[3];
  const float* Wg1   = (const float*)d_in[4];
  const float* asrc1 = (const float*)d_in[5];
  const float* adst1 = (const float*)d_in[6];
  const float* b1    = (const float*)d_in[7];
  const float* Wg2   = (const float*)d_in[8];
  const float* asrc2 = (const float*)d_in[9];
  const float* adst2 = (const float*)d_in[10];
  const float* b2    = (const float*)d_in[11];
  const float* fcW   = (const float*)d_in[12];
  const float* fcb   = (const float*)d_in[13];
  const float* outW  = (const float*)d_in[14];
  const float* outb  = (const float*)d_in[15];
  float* outp = (float*)d_out;

  const int E = in_sizes[1] / 2;      // 524288
  const int Etot = E + L;             // + self loops

  // ---- workspace layout ----
  char* ws = (char*)d_ws;
  __hip_bfloat16* mlp1 = (__hip_bfloat16*)(ws + 0);           // [L,1024] 16MB (dead after x0 GEMM)
  __hip_bfloat16* agg2 = (__hip_bfloat16*)(ws + 0);           // [L,1024] 16MB (after mlp1 dead)
  __hip_bfloat16* x0   = (__hip_bfloat16*)(ws + (24u << 20)); // [L,256] 4MB
  __hip_bfloat16* h1   = (__hip_bfloat16*)(ws + (28u << 20)); // [L,256] 4MB
  __hip_bfloat16* out1 = (__hip_bfloat16*)(ws + (32u << 20)); // [L,256] 4MB
  size_t off = (36u << 20);
  __hip_bfloat16* xb   = (__hip_bfloat16*)(ws + off); off += (size_t)L * 32 * 2;
  __hip_bfloat16* W1t  = (__hip_bfloat16*)(ws + off); off += (size_t)1024 * 32 * 2;
  __hip_bfloat16* W2t  = (__hip_bfloat16*)(ws + off); off += (size_t)256 * 1024 * 2;
  __hip_bfloat16* Wg1t = (__hip_bfloat16*)(ws + off); off += (size_t)320 * 256 * 2;  // extended
  __hip_bfloat16* Wg2t = (__hip_bfloat16*)(ws + off); off += (size_t)512 * 256 * 2;
  float* fcWt  = (float*)(ws + off); off += (size_t)512 * 512 * 4;
  float* outWt = (float*)(ws + off); off += (size_t)512 * 512 * 4;
  int* csr_src = (int*)(ws + off); off += (size_t)Etot * 4;
  int* rank    = (int*)(ws + off); off += (size_t)Etot * 4;
  off = (off + 255) & ~(size_t)255;
  int* row_start = (int*)(ws + off); off += (size_t)(L + 1) * 4;
  off = (off + 255) & ~(size_t)255;
  int* deg    = (int*)(ws + off); off += (size_t)L * 4;
  float* a_sd1 = (float*)(ws + off); off += (size_t)L * 8 * 4;
  float* a_sd2 = (float*)(ws + off); off += (size_t)L * 8 * 4;
  float* wa2 = (float*)(ws + off); off += 2048 * 4;
  float* pooled = (float*)(ws + off); off += 512 * 4;
  float* hbuf   = (float*)(ws + off); off += 512 * 4;

  // ---- zero deg ----
  hipMemsetAsync(deg, 0, (size_t)L * 4, stream);

  // ---- merged transposes + conversions + wa (wave-parallel) + degree/rank ----
  int tailB = 1024 + 512 + 512 + 56 + (Etot + 255) / 256;
  conv_combo<<<992 + tailB, 256, 0, stream>>>(
      seq, W1, W2, Wg1, Wg2, fcW, outW, ei, asrc1, adst1, asrc2, adst2, E, Etot,
      xb, W1t, W2t, Wg1t, Wg2t, fcWt, outWt, wa2, deg, rank);

  // ---- CSR ----
  scan_deg<<<1, 1024, 0, stream>>>(deg, row_start, pooled);
  scatter_edges<<<(Etot + 255) / 256, 256, 0, stream>>>(ei, E, Etot, row_start, rank, csr_src);

  // ---- input MLP ----
  gemm_big<32, true, false><<<dim3(16, 64), 256, 0, stream>>>(xb, W1t, mlp1, nullptr, L, 1024, 32);
  gemm_big<64, false, false><<<dim3(4, 64), 256, 0, stream>>>(mlp1, W2t, x0, nullptr, L, 256, 1024);

  // ---- GAT layer 1 (C=64): h1 GEMM also emits a_sd1 via extended Wg1t ----
  gemm_big<64, false, true><<<dim3(5, 64), 256, 0, stream>>>(x0, Wg1t, h1, a_sd1, L, 256, 256);
  gat_fused<64, true><<<4096, 128, 0, stream>>>(h1, a_sd1, row_start, csr_src, b1, out1, wa2, a_sd2);

  // ---- GAT layer 2: aggregate out1 (deferred projection), then per-head GEMM
  //      with fused bias+ReLU+column-sum into pooled ----
  gat_agg<<<4096, 128, 0, stream>>>(out1, a_sd2, row_start, csr_src, agg2);
  gemm_head<<<dim3(2, 64, 4), 256, 0, stream>>>(agg2, Wg2t, b2, pooled);

  // ---- FC head ----
  fc1<<<32, 256, 0, stream>>>(pooled, fcWt, fcb, hbuf);
  fc2<<<31, 256, 0, stream>>>(hbuf, outWt, outb, outp);
}